// Round 1
// baseline (826.469 us; speedup 1.0000x reference)
//
#include <hip/hip_runtime.h>

// ---------------------------------------------------------------------------
// GraphVAE (3x TransformerConv + LN/ReLU + mean-pool + classifier), f32.
// Structure per call:
//   CSR build (hist -> scan -> fill) over dst  [reused by all 3 layers]
//   per layer: gemm(q,k,v,skip) -> edge logits -> node softmax+aggregate -> ln/relu
//   pool -> classifier
// ---------------------------------------------------------------------------

#define WAVE 64

__global__ __launch_bounds__(256) void hist_kernel(const int* __restrict__ dst,
                                                   int* __restrict__ cnt, int E) {
    int e = blockIdx.x * 256 + threadIdx.x;
    if (e < E) atomicAdd(&cnt[dst[e]], 1);
}

// single-block scan: wave shfl-scan + serial wave-offset combine
__global__ __launch_bounds__(1024) void scan_kernel(const int* __restrict__ cnt,
                                                    int* __restrict__ rowptr, int n) {
    __shared__ int wls[16];
    __shared__ int carry;
    const int tid = threadIdx.x, lane = tid & 63, wid = tid >> 6;
    if (tid == 0) { carry = 0; rowptr[0] = 0; }
    __syncthreads();
    for (int base = 0; base < n; base += 1024) {
        int i = base + tid;
        int v = (i < n) ? cnt[i] : 0;
        int sc = v;
        for (int off = 1; off < 64; off <<= 1) {
            int t = __shfl_up(sc, off);
            if (lane >= off) sc += t;
        }
        if (lane == 63) wls[wid] = sc;
        __syncthreads();
        if (tid == 0) {
            int run = carry;
            for (int w2 = 0; w2 < 16; ++w2) { int t = wls[w2]; wls[w2] = run; run += t; }
            carry = run;
        }
        __syncthreads();
        if (i < n) rowptr[i + 1] = wls[wid] + sc;
        __syncthreads();
    }
}

__global__ __launch_bounds__(256) void fill_kernel(const int* __restrict__ dst,
                                                   const int* __restrict__ rowptr,
                                                   int* __restrict__ tmp,
                                                   int* __restrict__ eids, int E) {
    int e = blockIdx.x * 256 + threadIdx.x;
    if (e < E) {
        int d = dst[e];
        int p = atomicAdd(&tmp[d], 1);
        eids[rowptr[d] + p] = e;
    }
}

// ---------------------------------------------------------------------------
// GEMM: OUT = X @ W + b for 4 weight matrices (q,k,v,skip), K = 128.
// 64 rows x 64 cols per block, full-K LDS, 4x4 microtile per thread.
// blockIdx.y in [0,8): w = y>>1 selects matrix, (y&1)*64 selects col half.
// ---------------------------------------------------------------------------
__global__ __launch_bounds__(256) void gemm_qkvs_kernel(
    const float* __restrict__ X,
    const float* __restrict__ Wq, const float* __restrict__ Wk,
    const float* __restrict__ Wv, const float* __restrict__ Ws,
    const float* __restrict__ bq, const float* __restrict__ bk,
    const float* __restrict__ bv, const float* __restrict__ bs,
    float* __restrict__ qo, float* __restrict__ ko,
    float* __restrict__ vo, float* __restrict__ so, int nrows) {
    __shared__ float As[64][132];   // [row][k], pad to de-conflict
    __shared__ float Bs[128][64];   // [k][col]
    const int tid = threadIdx.x;
    const int row0 = blockIdx.x * 64;
    const int cb = blockIdx.y;
    const int w = cb >> 1;
    const int colbase = (cb & 1) * 64;
    const float* W    = (w == 0) ? Wq : (w == 1) ? Wk : (w == 2) ? Wv : Ws;
    const float* bias = (w == 0) ? bq : (w == 1) ? bk : (w == 2) ? bv : bs;
    float* OUT        = (w == 0) ? qo : (w == 1) ? ko : (w == 2) ? vo : so;

    // load A tile: 64 rows x 128 k
#pragma unroll
    for (int it = 0; it < 8; ++it) {
        int f = tid + it * 256;          // float4 index in [0,2048)
        int r = f >> 5;                  // 32 float4 per row
        int kq = f & 31;
        int row = row0 + r;
        float4 a = (row < nrows) ? *(const float4*)&X[(size_t)row * 128 + kq * 4]
                                 : make_float4(0.f, 0.f, 0.f, 0.f);
        *(float4*)&As[r][kq * 4] = a;
    }
    // load B tile: 128 k x 64 cols
#pragma unroll
    for (int it = 0; it < 8; ++it) {
        int f = tid + it * 256;          // float4 index in [0,2048)
        int kk = f >> 4;                 // 16 float4 per k-row
        int cq = f & 15;
        float4 b = *(const float4*)&W[(size_t)kk * 128 + colbase + cq * 4];
        *(float4*)&Bs[kk][cq * 4] = b;
    }
    __syncthreads();

    const int r0 = (tid >> 4) * 4;
    const int c0 = (tid & 15) * 4;
    float acc[4][4] = {};
#pragma unroll 8
    for (int kk = 0; kk < 128; ++kk) {
        const float4 b = *(const float4*)&Bs[kk][c0];
        const float a0 = As[r0 + 0][kk];
        const float a1 = As[r0 + 1][kk];
        const float a2 = As[r0 + 2][kk];
        const float a3 = As[r0 + 3][kk];
        acc[0][0] += a0 * b.x; acc[0][1] += a0 * b.y; acc[0][2] += a0 * b.z; acc[0][3] += a0 * b.w;
        acc[1][0] += a1 * b.x; acc[1][1] += a1 * b.y; acc[1][2] += a1 * b.z; acc[1][3] += a1 * b.w;
        acc[2][0] += a2 * b.x; acc[2][1] += a2 * b.y; acc[2][2] += a2 * b.z; acc[2][3] += a2 * b.w;
        acc[3][0] += a3 * b.x; acc[3][1] += a3 * b.y; acc[3][2] += a3 * b.z; acc[3][3] += a3 * b.w;
    }
    const float4 bb = *(const float4*)&bias[colbase + c0];
#pragma unroll
    for (int i = 0; i < 4; ++i) {
        int row = row0 + r0 + i;
        if (row < nrows) {
            float4 o;
            o.x = acc[i][0] + bb.x; o.y = acc[i][1] + bb.y;
            o.z = acc[i][2] + bb.z; o.w = acc[i][3] + bb.w;
            *(float4*)&OUT[(size_t)row * 128 + colbase + c0] = o;
        }
    }
}

// ---------------------------------------------------------------------------
// Edge logits: one wave per edge. lane handles 2 feature dims (c = 2*lane),
// head h = lane>>4; 16-lane-group shfl reduce -> logit[e][h].
// ---------------------------------------------------------------------------
__global__ __launch_bounds__(256) void edge_logit_kernel(
    const float* __restrict__ q, const float* __restrict__ k,
    const float* __restrict__ attr, const float* __restrict__ Wev,
    const float* __restrict__ bev,
    const int* __restrict__ src, const int* __restrict__ dst,
    float* __restrict__ alpha, int E) {
    const int e = blockIdx.x * 4 + (threadIdx.x >> 6);
    if (e >= E) return;
    const int lane = threadIdx.x & 63;
    const int s = src[e], d = dst[e];
    const float a = attr[e];
    const int c = lane * 2;
    const float2 qv = *(const float2*)&q[(size_t)d * 128 + c];
    const float2 kv = *(const float2*)&k[(size_t)s * 128 + c];
    const float2 wv = *(const float2*)&Wev[c];
    const float2 bv = *(const float2*)&bev[c];
    float p = qv.x * (kv.x + a * wv.x + bv.x) + qv.y * (kv.y + a * wv.y + bv.y);
    p += __shfl_xor(p, 1);
    p += __shfl_xor(p, 2);
    p += __shfl_xor(p, 4);
    p += __shfl_xor(p, 8);
    if ((lane & 15) == 0)
        alpha[(size_t)e * 4 + (lane >> 4)] = p * 0.17677669529663687f;  // 1/sqrt(32)
}

// ---------------------------------------------------------------------------
// Node softmax + aggregation: one wave per node, edges via CSR. No atomics.
// alpha buffer: logits in, final alpha out (in place).
// out buffer holds skip on entry; we += the attention aggregate.
// ---------------------------------------------------------------------------
__global__ __launch_bounds__(256) void node_kernel(
    const float* __restrict__ vbuf, const float* __restrict__ attr,
    const float* __restrict__ Wev, const float* __restrict__ bev,
    const int* __restrict__ src, const int* __restrict__ rowptr,
    const int* __restrict__ eids,
    float* __restrict__ alpha, float* __restrict__ out, int n) {
    const int node = (blockIdx.x * 256 + threadIdx.x) >> 6;
    const int lane = threadIdx.x & 63;
    if (node >= n) return;
    const int start = rowptr[node], end = rowptr[node + 1];

    // phase 1: per-head max
    float m0 = -1e30f, m1 = -1e30f, m2 = -1e30f, m3 = -1e30f;
    for (int j = start + lane; j < end; j += 64) {
        const int e = eids[j];
        const float4 lg = *(const float4*)&alpha[(size_t)e * 4];
        m0 = fmaxf(m0, lg.x); m1 = fmaxf(m1, lg.y);
        m2 = fmaxf(m2, lg.z); m3 = fmaxf(m3, lg.w);
    }
    for (int off = 1; off < 64; off <<= 1) {
        m0 = fmaxf(m0, __shfl_xor(m0, off));
        m1 = fmaxf(m1, __shfl_xor(m1, off));
        m2 = fmaxf(m2, __shfl_xor(m2, off));
        m3 = fmaxf(m3, __shfl_xor(m3, off));
    }
    // phase 2: exp + sum (store exp in place)
    float s0 = 0.f, s1 = 0.f, s2 = 0.f, s3 = 0.f;
    for (int j = start + lane; j < end; j += 64) {
        const int e = eids[j];
        float4 lg = *(const float4*)&alpha[(size_t)e * 4];
        lg.x = __expf(lg.x - m0); lg.y = __expf(lg.y - m1);
        lg.z = __expf(lg.z - m2); lg.w = __expf(lg.w - m3);
        *(float4*)&alpha[(size_t)e * 4] = lg;
        s0 += lg.x; s1 += lg.y; s2 += lg.z; s3 += lg.w;
    }
    for (int off = 1; off < 64; off <<= 1) {
        s0 += __shfl_xor(s0, off); s1 += __shfl_xor(s1, off);
        s2 += __shfl_xor(s2, off); s3 += __shfl_xor(s3, off);
    }
    const float i0 = 1.f / (s0 + 1e-16f), i1 = 1.f / (s1 + 1e-16f);
    const float i2 = 1.f / (s2 + 1e-16f), i3 = 1.f / (s3 + 1e-16f);
    // phase 3: normalize -> final alpha
    for (int j = start + lane; j < end; j += 64) {
        const int e = eids[j];
        float4 ev = *(const float4*)&alpha[(size_t)e * 4];
        ev.x *= i0; ev.y *= i1; ev.z *= i2; ev.w *= i3;
        *(float4*)&alpha[(size_t)e * 4] = ev;
    }
    // phase 4: aggregate v[src] + ef weighted by alpha
    const float w0 = Wev[lane], w1 = Wev[64 + lane];
    const float bb0 = bev[lane], bb1 = bev[64 + lane];
    const int hlo = lane >> 5;  // head of dim c=lane (0/1); c=lane+64 -> +2
    float acc0 = 0.f, acc1 = 0.f;
    for (int j = start; j < end; ++j) {
        const int e = eids[j];
        const int sn = src[e];
        const float av = attr[e];
        const float al = alpha[(size_t)e * 4 + hlo];
        const float ah = alpha[(size_t)e * 4 + 2 + hlo];
        acc0 += al * (vbuf[(size_t)sn * 128 + lane] + av * w0 + bb0);
        acc1 += ah * (vbuf[(size_t)sn * 128 + 64 + lane] + av * w1 + bb1);
    }
    out[(size_t)node * 128 + lane] += acc0;
    out[(size_t)node * 128 + 64 + lane] += acc1;
}

__global__ __launch_bounds__(256) void ln_relu_kernel(float* __restrict__ h,
                                                      const float* __restrict__ g,
                                                      const float* __restrict__ b, int n) {
    const int row = (blockIdx.x * 256 + threadIdx.x) >> 6;
    const int lane = threadIdx.x & 63;
    if (row >= n) return;
    const float x0 = h[(size_t)row * 128 + lane];
    const float x1 = h[(size_t)row * 128 + 64 + lane];
    float s = x0 + x1;
    for (int off = 1; off < 64; off <<= 1) s += __shfl_xor(s, off);
    const float mu = s * (1.f / 128.f);
    const float d0 = x0 - mu, d1 = x1 - mu;
    float vs = d0 * d0 + d1 * d1;
    for (int off = 1; off < 64; off <<= 1) vs += __shfl_xor(vs, off);
    const float inv = rsqrtf(vs * (1.f / 128.f) + 1e-5f);
    h[(size_t)row * 128 + lane]      = fmaxf(d0 * inv * g[lane] + b[lane], 0.f);
    h[(size_t)row * 128 + 64 + lane] = fmaxf(d1 * inv * g[64 + lane] + b[64 + lane], 0.f);
}

// pool: block = 128 threads (one per column), 256 rows per block; batch sorted
__global__ __launch_bounds__(128) void pool_kernel(const float* __restrict__ z,
                                                   const int* __restrict__ batch,
                                                   float* __restrict__ pool,
                                                   int* __restrict__ gcnt, int n) {
    const int c = threadIdx.x;
    const int row0 = blockIdx.x * 256;
    if (row0 >= n) return;
    const int rend = min(row0 + 256, n);
    int cur = batch[row0];
    float acc = 0.f;
    int run = 0;
    for (int r = row0; r < rend; ++r) {
        const int g = batch[r];
        if (g != cur) {
            atomicAdd(&pool[cur * 128 + c], acc);
            if (c == 0) atomicAdd(&gcnt[cur], run);
            acc = 0.f; run = 0; cur = g;
        }
        acc += z[(size_t)r * 128 + c];
        ++run;
    }
    atomicAdd(&pool[cur * 128 + c], acc);
    if (c == 0) atomicAdd(&gcnt[cur], run);
}

__global__ __launch_bounds__(128) void classifier_kernel(
    const float* __restrict__ pool, const int* __restrict__ gcnt,
    const int* __restrict__ batch,
    const float* __restrict__ fc1_w, const float* __restrict__ fc1_b,
    const float* __restrict__ cg, const float* __restrict__ cbv,
    const float* __restrict__ fc2_w, const float* __restrict__ fc2_b,
    float* __restrict__ zsel, float* __restrict__ probs) {
    __shared__ float zp[8][128];
    __shared__ float hc[8][128];
    __shared__ float red[2];
    __shared__ float lgt[8][10];
    const int c = threadIdx.x;
    const int lane = c & 63, wid = c >> 6;
#pragma unroll
    for (int g = 0; g < 8; ++g)
        zp[g][c] = pool[g * 128 + c] / fmaxf((float)gcnt[g], 1.f);
    __syncthreads();
    zsel[c] = zp[batch[0]][c];

    float acc[8];
#pragma unroll
    for (int g = 0; g < 8; ++g) acc[g] = fc1_b[c];
    for (int k = 0; k < 128; ++k) {
        const float w = fc1_w[k * 128 + c];
#pragma unroll
        for (int g = 0; g < 8; ++g) acc[g] += zp[g][k] * w;
    }
#pragma unroll
    for (int g = 0; g < 8; ++g) {
        float s = acc[g];
        for (int off = 1; off < 64; off <<= 1) s += __shfl_xor(s, off);
        if (lane == 0) red[wid] = s;
        __syncthreads();
        const float mu = (red[0] + red[1]) * (1.f / 128.f);
        __syncthreads();
        const float d = acc[g] - mu;
        float s2 = d * d;
        for (int off = 1; off < 64; off <<= 1) s2 += __shfl_xor(s2, off);
        if (lane == 0) red[wid] = s2;
        __syncthreads();
        const float var = (red[0] + red[1]) * (1.f / 128.f);
        __syncthreads();
        hc[g][c] = fmaxf(d * rsqrtf(var + 1e-5f) * cg[c] + cbv[c], 0.f);
    }
    __syncthreads();
    if (c < 80) {
        const int g = c / 10, j = c - g * 10;
        float s = fc2_b[j];
        for (int k = 0; k < 128; ++k) s += hc[g][k] * fc2_w[k * 10 + j];
        lgt[g][j] = s;
    }
    __syncthreads();
    if (c < 8) {
        float mx = -1e30f;
#pragma unroll
        for (int j = 0; j < 10; ++j) mx = fmaxf(mx, lgt[c][j]);
        float ex[10];
        float sum = 0.f;
#pragma unroll
        for (int j = 0; j < 10; ++j) { ex[j] = expf(lgt[c][j] - mx); sum += ex[j]; }
#pragma unroll
        for (int j = 0; j < 10; ++j) probs[c * 10 + j] = ex[j] / sum;
    }
}

// ---------------------------------------------------------------------------

extern "C" void kernel_launch(void* const* d_in, const int* in_sizes, int n_in,
                              void* d_out, int out_size, void* d_ws, size_t ws_size,
                              hipStream_t stream) {
    const float* x = (const float*)d_in[0];
    const int* edge_index = (const int*)d_in[1];
    const float* attr = (const float*)d_in[2];
    const int* batch = (const int*)d_in[3];
    const int N = in_sizes[0] / 128;
    const int E = in_sizes[2];
    const int* src = edge_index;
    const int* dst = edge_index + E;

    const float *Wq[3], *Wk[3], *Wv[3], *We[3], *Ws[3];
    const float *bq[3], *bk[3], *bv[3], *be[3], *bs[3];
    int idx = 4;
    for (int l = 0; l < 3; ++l) {
        Wq[l] = (const float*)d_in[idx++];
        Wk[l] = (const float*)d_in[idx++];
        Wv[l] = (const float*)d_in[idx++];
        We[l] = (const float*)d_in[idx++];
        Ws[l] = (const float*)d_in[idx++];
        bq[l] = (const float*)d_in[idx++];
        bk[l] = (const float*)d_in[idx++];
        bv[l] = (const float*)d_in[idx++];
        be[l] = (const float*)d_in[idx++];
        bs[l] = (const float*)d_in[idx++];
    }
    const float* ln_g[2] = {(const float*)d_in[34], (const float*)d_in[36]};
    const float* ln_b[2] = {(const float*)d_in[35], (const float*)d_in[37]};
    const float* fc1_w = (const float*)d_in[38];
    const float* fc1_b = (const float*)d_in[39];
    const float* cln_g = (const float*)d_in[40];
    const float* cln_b = (const float*)d_in[41];
    const float* fc2_w = (const float*)d_in[42];
    const float* fc2_b = (const float*)d_in[43];
    const int C = in_sizes[43];

    float* out = (float*)d_out;
    float* z_out = out;
    float* zsel_out = out + (size_t)N * 128;
    float* probs_out = zsel_out + 128;
    const int GC = out_size - N * 128 - 128 - 3 * E * 4;
    const int G = GC / C;  // = 8
    float* alpha_out[3];
    alpha_out[0] = probs_out + GC;
    alpha_out[1] = alpha_out[0] + (size_t)E * 4;
    alpha_out[2] = alpha_out[1] + (size_t)E * 4;

    // workspace layout
    char* p = (char*)d_ws;
    auto alloc = [&](size_t bytes) {
        void* r = (void*)p;
        p += (bytes + 255) & ~(size_t)255;
        return r;
    };
    float* qb = (float*)alloc((size_t)N * 128 * 4);
    float* kb = (float*)alloc((size_t)N * 128 * 4);
    float* vb = (float*)alloc((size_t)N * 128 * 4);
    float* hA = (float*)alloc((size_t)N * 128 * 4);
    float* hB = (float*)alloc((size_t)N * 128 * 4);
    int* counts = (int*)alloc((size_t)N * 4);
    int* rowptr = (int*)alloc((size_t)(N + 1) * 4);
    int* cnt2 = (int*)alloc((size_t)N * 4);
    int* eids = (int*)alloc((size_t)E * 4);
    float* pool = (float*)alloc((size_t)G * 128 * 4);
    int* gcnt = (int*)alloc((size_t)G * 4);

    hipMemsetAsync(counts, 0, (size_t)N * 4, stream);
    hipMemsetAsync(cnt2, 0, (size_t)N * 4, stream);
    hipMemsetAsync(pool, 0, (size_t)G * 128 * 4, stream);
    hipMemsetAsync(gcnt, 0, (size_t)G * 4, stream);

    // CSR over dst
    hist_kernel<<<(E + 255) / 256, 256, 0, stream>>>(dst, counts, E);
    scan_kernel<<<1, 1024, 0, stream>>>(counts, rowptr, N);
    fill_kernel<<<(E + 255) / 256, 256, 0, stream>>>(dst, rowptr, cnt2, eids, E);

    const float* Xl = x;
    for (int l = 0; l < 3; ++l) {
        float* OUTl = (l == 0) ? hA : (l == 1) ? hB : z_out;
        gemm_qkvs_kernel<<<dim3((N + 63) / 64, 8), 256, 0, stream>>>(
            Xl, Wq[l], Wk[l], Wv[l], Ws[l], bq[l], bk[l], bv[l], bs[l],
            qb, kb, vb, OUTl, N);
        edge_logit_kernel<<<(E + 3) / 4, 256, 0, stream>>>(
            qb, kb, attr, We[l], be[l], src, dst, alpha_out[l], E);
        node_kernel<<<(N * 64 + 255) / 256, 256, 0, stream>>>(
            vb, attr, We[l], be[l], src, rowptr, eids, alpha_out[l], OUTl, N);
        if (l < 2)
            ln_relu_kernel<<<((N + 3) / 4), 256, 0, stream>>>(OUTl, ln_g[l], ln_b[l], N);
        Xl = OUTl;
    }

    pool_kernel<<<(N + 255) / 256, 128, 0, stream>>>(z_out, batch, pool, gcnt, N);
    classifier_kernel<<<1, 128, 0, stream>>>(pool, gcnt, batch, fc1_w, fc1_b,
                                             cln_g, cln_b, fc2_w, fc2_b,
                                             zsel_out, probs_out);
}

// Round 4
// 552.053 us; speedup vs baseline: 1.4971x; 1.4971x over previous
//
#include <hip/hip_runtime.h>

// ---------------------------------------------------------------------------
// GraphVAE (3x TransformerConv + LN/ReLU + mean-pool + classifier), f32 + bf16 k/v.
// Per call:
//   CSR build over dst (hist -> scan -> fill, with permuted src/attr/eid)
//   per layer: gemm(q f32, k bf16, v bf16, skip f32) -> fused node kernel
//              (logits + segment softmax + weighted aggregate) -> ln/relu
//   pool -> classifier
// NOTE: alpha transpose in pass C goes through LDS (alds) — NOT cross-lane
// shfl with head-dependent operand (divergent shfl from possibly-inactive
// source lane is undefined; caused round-2 failure).
// ---------------------------------------------------------------------------

__device__ __forceinline__ unsigned pack_bf16_rne(float a, float b) {
    unsigned ua = __float_as_uint(a);
    ua += 0x7fffu + ((ua >> 16) & 1u);
    unsigned ub = __float_as_uint(b);
    ub += 0x7fffu + ((ub >> 16) & 1u);
    return (ua >> 16) | (ub & 0xffff0000u);
}

__global__ __launch_bounds__(256) void hist_kernel(const int* __restrict__ dst,
                                                   int* __restrict__ cnt, int E) {
    int e = blockIdx.x * 256 + threadIdx.x;
    if (e < E) atomicAdd(&cnt[dst[e]], 1);
}

// single-block scan: wave shfl-scan + serial wave-offset combine
__global__ __launch_bounds__(1024) void scan_kernel(const int* __restrict__ cnt,
                                                    int* __restrict__ rowptr, int n) {
    __shared__ int wls[16];
    __shared__ int carry;
    const int tid = threadIdx.x, lane = tid & 63, wid = tid >> 6;
    if (tid == 0) { carry = 0; rowptr[0] = 0; }
    __syncthreads();
    for (int base = 0; base < n; base += 1024) {
        int i = base + tid;
        int v = (i < n) ? cnt[i] : 0;
        int sc = v;
        for (int off = 1; off < 64; off <<= 1) {
            int t = __shfl_up(sc, off);
            if (lane >= off) sc += t;
        }
        if (lane == 63) wls[wid] = sc;
        __syncthreads();
        if (tid == 0) {
            int run = carry;
            for (int w2 = 0; w2 < 16; ++w2) { int t = wls[w2]; wls[w2] = run; run += t; }
            carry = run;
        }
        __syncthreads();
        if (i < n) rowptr[i + 1] = wls[wid] + sc;
        __syncthreads();
    }
}

__global__ __launch_bounds__(256) void fill_kernel(const int* __restrict__ src,
                                                   const int* __restrict__ dst,
                                                   const float* __restrict__ attr,
                                                   const int* __restrict__ rowptr,
                                                   int* __restrict__ tmp,
                                                   int* __restrict__ src_perm,
                                                   float* __restrict__ attr_perm,
                                                   int* __restrict__ eidp, int E) {
    int e = blockIdx.x * 256 + threadIdx.x;
    if (e < E) {
        int d = dst[e];
        int p = atomicAdd(&tmp[d], 1);
        int pos = rowptr[d] + p;
        src_perm[pos] = src[e];
        attr_perm[pos] = attr[e];
        eidp[pos] = e;
    }
}

// ---------------------------------------------------------------------------
// GEMM: OUT = X @ W + b for q (f32), k (bf16), v (bf16), skip (f32). K = 128.
// 64 rows x 64 cols per block, full-K LDS, 4x4 microtile per thread.
// blockIdx.y in [0,8): w = y>>1 selects matrix, (y&1)*64 selects col half.
// ---------------------------------------------------------------------------
__global__ __launch_bounds__(256) void gemm_qkvs_kernel(
    const float* __restrict__ X,
    const float* __restrict__ Wq, const float* __restrict__ Wk,
    const float* __restrict__ Wv, const float* __restrict__ Ws,
    const float* __restrict__ bq, const float* __restrict__ bk,
    const float* __restrict__ bv, const float* __restrict__ bs,
    float* __restrict__ qo, unsigned* __restrict__ ko,
    unsigned* __restrict__ vo, float* __restrict__ so, int nrows) {
    __shared__ float As[64][132];
    __shared__ float Bs[128][64];
    const int tid = threadIdx.x;
    const int row0 = blockIdx.x * 64;
    const int cb = blockIdx.y;
    const int w = cb >> 1;
    const int colbase = (cb & 1) * 64;
    const float* W    = (w == 0) ? Wq : (w == 1) ? Wk : (w == 2) ? Wv : Ws;
    const float* bias = (w == 0) ? bq : (w == 1) ? bk : (w == 2) ? bv : bs;

#pragma unroll
    for (int it = 0; it < 8; ++it) {
        int f = tid + it * 256;
        int r = f >> 5;
        int kq = f & 31;
        int row = row0 + r;
        float4 a = (row < nrows) ? *(const float4*)&X[(size_t)row * 128 + kq * 4]
                                 : make_float4(0.f, 0.f, 0.f, 0.f);
        *(float4*)&As[r][kq * 4] = a;
    }
#pragma unroll
    for (int it = 0; it < 8; ++it) {
        int f = tid + it * 256;
        int kk = f >> 4;
        int cq = f & 15;
        float4 b = *(const float4*)&W[(size_t)kk * 128 + colbase + cq * 4];
        *(float4*)&Bs[kk][cq * 4] = b;
    }
    __syncthreads();

    const int r0 = (tid >> 4) * 4;
    const int c0 = (tid & 15) * 4;
    float acc[4][4] = {};
#pragma unroll 8
    for (int kk = 0; kk < 128; ++kk) {
        const float4 b = *(const float4*)&Bs[kk][c0];
        const float a0 = As[r0 + 0][kk];
        const float a1 = As[r0 + 1][kk];
        const float a2 = As[r0 + 2][kk];
        const float a3 = As[r0 + 3][kk];
        acc[0][0] += a0 * b.x; acc[0][1] += a0 * b.y; acc[0][2] += a0 * b.z; acc[0][3] += a0 * b.w;
        acc[1][0] += a1 * b.x; acc[1][1] += a1 * b.y; acc[1][2] += a1 * b.z; acc[1][3] += a1 * b.w;
        acc[2][0] += a2 * b.x; acc[2][1] += a2 * b.y; acc[2][2] += a2 * b.z; acc[2][3] += a2 * b.w;
        acc[3][0] += a3 * b.x; acc[3][1] += a3 * b.y; acc[3][2] += a3 * b.z; acc[3][3] += a3 * b.w;
    }
    const float4 bb = *(const float4*)&bias[colbase + c0];
    if (w == 0 || w == 3) {
        float* OUT = (w == 0) ? qo : so;
#pragma unroll
        for (int i = 0; i < 4; ++i) {
            int row = row0 + r0 + i;
            if (row < nrows) {
                float4 o;
                o.x = acc[i][0] + bb.x; o.y = acc[i][1] + bb.y;
                o.z = acc[i][2] + bb.z; o.w = acc[i][3] + bb.w;
                *(float4*)&OUT[(size_t)row * 128 + colbase + c0] = o;
            }
        }
    } else {
        unsigned* OUT = (w == 1) ? ko : vo;
#pragma unroll
        for (int i = 0; i < 4; ++i) {
            int row = row0 + r0 + i;
            if (row < nrows) {
                unsigned u0 = pack_bf16_rne(acc[i][0] + bb.x, acc[i][1] + bb.y);
                unsigned u1 = pack_bf16_rne(acc[i][2] + bb.z, acc[i][3] + bb.w);
                *(uint2*)&OUT[(size_t)row * 64 + ((colbase + c0) >> 1)] = make_uint2(u0, u1);
            }
        }
    }
}

// ---------------------------------------------------------------------------
// Fused node kernel: one wave per node (4 waves/block). Per node:
//   pass A: gather k[src] (bf16), 4-head logits -> alpha_perm, reg running max.
//   pass B: reload logits (L2-hot), exp, wave sum, store exp back.
//   pass C: normalize -> alpha_out[orig e] (per-lane float4, no shfl);
//           LDS-transpose alpha -> scalar broadcast reads; gather v[src] (bf16),
//           accumulate alpha * (v + ef); out += (out holds skip).
// Lane layout: lane l owns dims (2l, 2l+1); head h = l>>4.
// ---------------------------------------------------------------------------
__global__ __launch_bounds__(256) void node_fused_kernel(
    const float* __restrict__ qb, const unsigned* __restrict__ kb,
    const unsigned* __restrict__ vb,
    const float* __restrict__ Wev, const float* __restrict__ bev,
    const int* __restrict__ rowptr, const int* __restrict__ src_perm,
    const float* __restrict__ attr_perm, const int* __restrict__ eidp,
    float* __restrict__ alpha_perm, float* __restrict__ alpha_out,
    float* __restrict__ out, int n) {
    __shared__ float alds[4][64][4];
    const int wid = threadIdx.x >> 6;
    const int node = blockIdx.x * 4 + wid;
    const int lane = threadIdx.x & 63;
    if (node >= n) return;
    const int start = rowptr[node], end = rowptr[node + 1];
    if (start == end) return;  // no incoming edges: out keeps skip, no alpha

    const float we0 = Wev[2 * lane], we1 = Wev[2 * lane + 1];
    const float be0 = bev[2 * lane], be1 = bev[2 * lane + 1];
    const float2 qv = *(const float2*)&qb[(size_t)node * 128 + 2 * lane];
    const float scale = 0.17677669529663687f;  // 1/sqrt(32)

    // ---- pass A: logits + per-head running max ----
    float mh = -1e30f;
    for (int c0 = start; c0 < end; c0 += 64) {
        const int nc = min(64, end - c0);
        const int sj = (lane < nc) ? src_perm[c0 + lane] : 0;
        const float aj = (lane < nc) ? attr_perm[c0 + lane] : 0.f;
        int t = 0;
        for (; t + 1 < nc; t += 2) {
            const int s0 = __shfl(sj, t), s1 = __shfl(sj, t + 1);
            const float a0 = __shfl(aj, t), a1 = __shfl(aj, t + 1);
            const unsigned u0 = kb[(size_t)s0 * 64 + lane];
            const unsigned u1 = kb[(size_t)s1 * 64 + lane];
            float p0 = qv.x * (__uint_as_float(u0 << 16) + a0 * we0 + be0)
                     + qv.y * (__uint_as_float(u0 & 0xffff0000u) + a0 * we1 + be1);
            float p1 = qv.x * (__uint_as_float(u1 << 16) + a1 * we0 + be0)
                     + qv.y * (__uint_as_float(u1 & 0xffff0000u) + a1 * we1 + be1);
#pragma unroll
            for (int off = 1; off < 16; off <<= 1) {
                p0 += __shfl_xor(p0, off);
                p1 += __shfl_xor(p1, off);
            }
            p0 *= scale; p1 *= scale;
            mh = fmaxf(mh, fmaxf(p0, p1));
            if ((lane & 15) == 0) {
                alpha_perm[(size_t)(c0 + t) * 4 + (lane >> 4)] = p0;
                alpha_perm[(size_t)(c0 + t + 1) * 4 + (lane >> 4)] = p1;
            }
        }
        if (t < nc) {
            const int s0 = __shfl(sj, t);
            const float a0 = __shfl(aj, t);
            const unsigned u0 = kb[(size_t)s0 * 64 + lane];
            float p0 = qv.x * (__uint_as_float(u0 << 16) + a0 * we0 + be0)
                     + qv.y * (__uint_as_float(u0 & 0xffff0000u) + a0 * we1 + be1);
#pragma unroll
            for (int off = 1; off < 16; off <<= 1) p0 += __shfl_xor(p0, off);
            p0 *= scale;
            mh = fmaxf(mh, p0);
            if ((lane & 15) == 0)
                alpha_perm[(size_t)(c0 + t) * 4 + (lane >> 4)] = p0;
        }
    }
    const float m0 = __shfl(mh, 0), m1 = __shfl(mh, 16);
    const float m2 = __shfl(mh, 32), m3 = __shfl(mh, 48);

    // ---- pass B: exp + per-head sum ----
    float4 s4 = make_float4(0.f, 0.f, 0.f, 0.f);
    for (int c0 = start; c0 < end; c0 += 64) {
        const int j = c0 + lane;
        if (j < end) {
            float4 lg = *(const float4*)&alpha_perm[(size_t)j * 4];
            lg.x = __expf(lg.x - m0); lg.y = __expf(lg.y - m1);
            lg.z = __expf(lg.z - m2); lg.w = __expf(lg.w - m3);
            *(float4*)&alpha_perm[(size_t)j * 4] = lg;
            s4.x += lg.x; s4.y += lg.y; s4.z += lg.z; s4.w += lg.w;
        }
    }
#pragma unroll
    for (int off = 1; off < 64; off <<= 1) {
        s4.x += __shfl_xor(s4.x, off); s4.y += __shfl_xor(s4.y, off);
        s4.z += __shfl_xor(s4.z, off); s4.w += __shfl_xor(s4.w, off);
    }
    const float i0 = 1.f / (s4.x + 1e-16f), i1 = 1.f / (s4.y + 1e-16f);
    const float i2 = 1.f / (s4.z + 1e-16f), i3 = 1.f / (s4.w + 1e-16f);
    const int h = lane >> 4;

    // ---- pass C: normalize alpha -> output order; LDS transpose; aggregate ----
    float acc0 = 0.f, acc1 = 0.f;
    for (int c0 = start; c0 < end; c0 += 64) {
        const int nc = min(64, end - c0);
        const int j = c0 + lane;
        if (lane < nc) {
            float4 ex = *(const float4*)&alpha_perm[(size_t)j * 4];
            float4 al;
            al.x = ex.x * i0; al.y = ex.y * i1; al.z = ex.z * i2; al.w = ex.w * i3;
            *(float4*)&alpha_out[(size_t)eidp[j] * 4] = al;
            *(float4*)&alds[wid][lane][0] = al;
        }
        const int sj = (lane < nc) ? src_perm[j] : 0;
        const float aj = (lane < nc) ? attr_perm[j] : 0.f;
        int t = 0;
        for (; t + 1 < nc; t += 2) {
            const int s0 = __shfl(sj, t), s1 = __shfl(sj, t + 1);
            const float a0 = __shfl(aj, t), a1 = __shfl(aj, t + 1);
            const float w0 = alds[wid][t][h];
            const float w1 = alds[wid][t + 1][h];
            const unsigned u0 = vb[(size_t)s0 * 64 + lane];
            const unsigned u1 = vb[(size_t)s1 * 64 + lane];
            acc0 += w0 * (__uint_as_float(u0 << 16) + a0 * we0 + be0)
                  + w1 * (__uint_as_float(u1 << 16) + a1 * we0 + be0);
            acc1 += w0 * (__uint_as_float(u0 & 0xffff0000u) + a0 * we1 + be1)
                  + w1 * (__uint_as_float(u1 & 0xffff0000u) + a1 * we1 + be1);
        }
        if (t < nc) {
            const int s0 = __shfl(sj, t);
            const float a0 = __shfl(aj, t);
            const float w0 = alds[wid][t][h];
            const unsigned u0 = vb[(size_t)s0 * 64 + lane];
            acc0 += w0 * (__uint_as_float(u0 << 16) + a0 * we0 + be0);
            acc1 += w0 * (__uint_as_float(u0 & 0xffff0000u) + a0 * we1 + be1);
        }
    }
    float2 o = *(float2*)&out[(size_t)node * 128 + 2 * lane];
    o.x += acc0; o.y += acc1;
    *(float2*)&out[(size_t)node * 128 + 2 * lane] = o;
}

__global__ __launch_bounds__(256) void ln_relu_kernel(float* __restrict__ h,
                                                      const float* __restrict__ g,
                                                      const float* __restrict__ b, int n) {
    const int row = (blockIdx.x * 256 + threadIdx.x) >> 6;
    const int lane = threadIdx.x & 63;
    if (row >= n) return;
    const float x0 = h[(size_t)row * 128 + lane];
    const float x1 = h[(size_t)row * 128 + 64 + lane];
    float s = x0 + x1;
    for (int off = 1; off < 64; off <<= 1) s += __shfl_xor(s, off);
    const float mu = s * (1.f / 128.f);
    const float d0 = x0 - mu, d1 = x1 - mu;
    float vs = d0 * d0 + d1 * d1;
    for (int off = 1; off < 64; off <<= 1) vs += __shfl_xor(vs, off);
    const float inv = rsqrtf(vs * (1.f / 128.f) + 1e-5f);
    h[(size_t)row * 128 + lane]      = fmaxf(d0 * inv * g[lane] + b[lane], 0.f);
    h[(size_t)row * 128 + 64 + lane] = fmaxf(d1 * inv * g[64 + lane] + b[64 + lane], 0.f);
}

// pool: one block per 32 rows, 128 threads (one per column); batch sorted
__global__ __launch_bounds__(128) void pool_kernel(const float* __restrict__ z,
                                                   const int* __restrict__ batch,
                                                   float* __restrict__ pool,
                                                   int* __restrict__ gcnt, int n) {
    const int c = threadIdx.x;
    const int row0 = blockIdx.x * 32;
    if (row0 >= n) return;
    const int rend = min(row0 + 32, n);
    int cur = batch[row0];
    float acc = 0.f;
    int run = 0;
    for (int r = row0; r < rend; ++r) {
        const int g = batch[r];
        if (g != cur) {
            atomicAdd(&pool[cur * 128 + c], acc);
            if (c == 0) atomicAdd(&gcnt[cur], run);
            acc = 0.f; run = 0; cur = g;
        }
        acc += z[(size_t)r * 128 + c];
        ++run;
    }
    atomicAdd(&pool[cur * 128 + c], acc);
    if (c == 0) atomicAdd(&gcnt[cur], run);
}

__global__ __launch_bounds__(128) void classifier_kernel(
    const float* __restrict__ pool, const int* __restrict__ gcnt,
    const int* __restrict__ batch,
    const float* __restrict__ fc1_w, const float* __restrict__ fc1_b,
    const float* __restrict__ cg, const float* __restrict__ cbv,
    const float* __restrict__ fc2_w, const float* __restrict__ fc2_b,
    float* __restrict__ zsel, float* __restrict__ probs) {
    __shared__ float zp[8][128];
    __shared__ float hc[8][128];
    __shared__ float red[2];
    __shared__ float lgt[8][10];
    const int c = threadIdx.x;
    const int lane = c & 63, wid = c >> 6;
#pragma unroll
    for (int g = 0; g < 8; ++g)
        zp[g][c] = pool[g * 128 + c] / fmaxf((float)gcnt[g], 1.f);
    __syncthreads();
    zsel[c] = zp[batch[0]][c];

    float acc[8];
#pragma unroll
    for (int g = 0; g < 8; ++g) acc[g] = fc1_b[c];
    for (int k = 0; k < 128; ++k) {
        const float w = fc1_w[k * 128 + c];
#pragma unroll
        for (int g = 0; g < 8; ++g) acc[g] += zp[g][k] * w;
    }
#pragma unroll
    for (int g = 0; g < 8; ++g) {
        float s = acc[g];
        for (int off = 1; off < 64; off <<= 1) s += __shfl_xor(s, off);
        if (lane == 0) red[wid] = s;
        __syncthreads();
        const float mu = (red[0] + red[1]) * (1.f / 128.f);
        __syncthreads();
        const float d = acc[g] - mu;
        float s2 = d * d;
        for (int off = 1; off < 64; off <<= 1) s2 += __shfl_xor(s2, off);
        if (lane == 0) red[wid] = s2;
        __syncthreads();
        const float var = (red[0] + red[1]) * (1.f / 128.f);
        __syncthreads();
        hc[g][c] = fmaxf(d * rsqrtf(var + 1e-5f) * cg[c] + cbv[c], 0.f);
    }
    __syncthreads();
    if (c < 80) {
        const int g = c / 10, j = c - g * 10;
        float s = fc2_b[j];
        for (int k = 0; k < 128; ++k) s += hc[g][k] * fc2_w[k * 10 + j];
        lgt[g][j] = s;
    }
    __syncthreads();
    if (c < 8) {
        float mx = -1e30f;
#pragma unroll
        for (int j = 0; j < 10; ++j) mx = fmaxf(mx, lgt[c][j]);
        float ex[10];
        float sum = 0.f;
#pragma unroll
        for (int j = 0; j < 10; ++j) { ex[j] = expf(lgt[c][j] - mx); sum += ex[j]; }
#pragma unroll
        for (int j = 0; j < 10; ++j) probs[c * 10 + j] = ex[j] / sum;
    }
}

// ---------------------------------------------------------------------------

extern "C" void kernel_launch(void* const* d_in, const int* in_sizes, int n_in,
                              void* d_out, int out_size, void* d_ws, size_t ws_size,
                              hipStream_t stream) {
    const float* x = (const float*)d_in[0];
    const int* edge_index = (const int*)d_in[1];
    const float* attr = (const float*)d_in[2];
    const int* batch = (const int*)d_in[3];
    const int N = in_sizes[0] / 128;
    const int E = in_sizes[2];
    const int* src = edge_index;
    const int* dst = edge_index + E;

    const float *Wq[3], *Wk[3], *Wv[3], *We[3], *Ws[3];
    const float *bq[3], *bk[3], *bv[3], *be[3], *bs[3];
    int idx = 4;
    for (int l = 0; l < 3; ++l) {
        Wq[l] = (const float*)d_in[idx++];
        Wk[l] = (const float*)d_in[idx++];
        Wv[l] = (const float*)d_in[idx++];
        We[l] = (const float*)d_in[idx++];
        Ws[l] = (const float*)d_in[idx++];
        bq[l] = (const float*)d_in[idx++];
        bk[l] = (const float*)d_in[idx++];
        bv[l] = (const float*)d_in[idx++];
        be[l] = (const float*)d_in[idx++];
        bs[l] = (const float*)d_in[idx++];
    }
    const float* ln_g[2] = {(const float*)d_in[34], (const float*)d_in[36]};
    const float* ln_b[2] = {(const float*)d_in[35], (const float*)d_in[37]};
    const float* fc1_w = (const float*)d_in[38];
    const float* fc1_b = (const float*)d_in[39];
    const float* cln_g = (const float*)d_in[40];
    const float* cln_b = (const float*)d_in[41];
    const float* fc2_w = (const float*)d_in[42];
    const float* fc2_b = (const float*)d_in[43];
    const int C = in_sizes[43];

    float* out = (float*)d_out;
    float* z_out = out;
    float* zsel_out = out + (size_t)N * 128;
    float* probs_out = zsel_out + 128;
    const int GC = out_size - N * 128 - 128 - 3 * E * 4;
    const int G = GC / C;  // = 8
    float* alpha_out[3];
    alpha_out[0] = probs_out + GC;
    alpha_out[1] = alpha_out[0] + (size_t)E * 4;
    alpha_out[2] = alpha_out[1] + (size_t)E * 4;

    // workspace layout
    char* p = (char*)d_ws;
    auto alloc = [&](size_t bytes) {
        void* r = (void*)p;
        p += (bytes + 255) & ~(size_t)255;
        return r;
    };
    float* qb = (float*)alloc((size_t)N * 128 * 4);
    unsigned* kb = (unsigned*)alloc((size_t)N * 64 * 4);
    unsigned* vb = (unsigned*)alloc((size_t)N * 64 * 4);
    float* hA = (float*)alloc((size_t)N * 128 * 4);
    float* hB = (float*)alloc((size_t)N * 128 * 4);
    int* counts = (int*)alloc((size_t)N * 4);
    int* rowptr = (int*)alloc((size_t)(N + 1) * 4);
    int* cnt2 = (int*)alloc((size_t)N * 4);
    int* src_perm = (int*)alloc((size_t)E * 4);
    float* attr_perm = (float*)alloc((size_t)E * 4);
    int* eidp = (int*)alloc((size_t)E * 4);
    float* alpha_perm = (float*)alloc((size_t)E * 4 * 4);
    float* pool = (float*)alloc((size_t)G * 128 * 4);
    int* gcnt = (int*)alloc((size_t)G * 4);

    hipMemsetAsync(counts, 0, (size_t)N * 4, stream);
    hipMemsetAsync(cnt2, 0, (size_t)N * 4, stream);
    hipMemsetAsync(pool, 0, (size_t)G * 128 * 4, stream);
    hipMemsetAsync(gcnt, 0, (size_t)G * 4, stream);

    // CSR over dst (+ permuted src/attr/eid)
    hist_kernel<<<(E + 255) / 256, 256, 0, stream>>>(dst, counts, E);
    scan_kernel<<<1, 1024, 0, stream>>>(counts, rowptr, N);
    fill_kernel<<<(E + 255) / 256, 256, 0, stream>>>(src, dst, attr, rowptr, cnt2,
                                                     src_perm, attr_perm, eidp, E);

    const float* Xl = x;
    for (int l = 0; l < 3; ++l) {
        float* OUTl = (l == 0) ? hA : (l == 1) ? hB : z_out;
        gemm_qkvs_kernel<<<dim3((N + 63) / 64, 8), 256, 0, stream>>>(
            Xl, Wq[l], Wk[l], Wv[l], Ws[l], bq[l], bk[l], bv[l], bs[l],
            qb, kb, vb, OUTl, N);
        node_fused_kernel<<<(N + 3) / 4, 256, 0, stream>>>(
            qb, kb, vb, We[l], be[l], rowptr, src_perm, attr_perm, eidp,
            alpha_perm, alpha_out[l], OUTl, N);
        if (l < 2)
            ln_relu_kernel<<<((N + 3) / 4), 256, 0, stream>>>(OUTl, ln_g[l], ln_b[l], N);
        Xl = OUTl;
    }

    pool_kernel<<<(N + 31) / 32, 128, 0, stream>>>(z_out, batch, pool, gcnt, N);
    classifier_kernel<<<1, 128, 0, stream>>>(pool, gcnt, batch, fc1_w, fc1_b,
                                             cln_g, cln_b, fc2_w, fc2_b,
                                             zsel_out, probs_out);
}

// Round 6
// 523.898 us; speedup vs baseline: 1.5775x; 1.0537x over previous
//
#include <hip/hip_runtime.h>

// ---------------------------------------------------------------------------
// GraphVAE (3x TransformerConv + LN/ReLU + mean-pool + classifier).
// Round 5 (resubmit): bf16 MFMA GEMMs (LDS-free, pre-transposed bf16 weights)
// + register-resident segment softmax in the fused node kernel (deg<=64 fast
// path, no alpha_perm traffic; 3-pass fallback for deg>64).
// ---------------------------------------------------------------------------

typedef short short8v __attribute__((ext_vector_type(8)));
typedef float f32x4 __attribute__((ext_vector_type(4)));

__device__ __forceinline__ unsigned pack_bf16_rne(float a, float b) {
    unsigned ua = __float_as_uint(a);
    ua += 0x7fffu + ((ua >> 16) & 1u);
    unsigned ub = __float_as_uint(b);
    ub += 0x7fffu + ((ub >> 16) & 1u);
    return (ua >> 16) | (ub & 0xffff0000u);
}

__device__ __forceinline__ unsigned short bf16_rne1(float a) {
    unsigned u = __float_as_uint(a);
    u += 0x7fffu + ((u >> 16) & 1u);
    return (unsigned short)(u >> 16);
}

__global__ __launch_bounds__(256) void hist_kernel(const int* __restrict__ dst,
                                                   int* __restrict__ cnt, int E) {
    int e = blockIdx.x * 256 + threadIdx.x;
    if (e < E) atomicAdd(&cnt[dst[e]], 1);
}

// single-block scan: wave shfl-scan + serial wave-offset combine
__global__ __launch_bounds__(1024) void scan_kernel(const int* __restrict__ cnt,
                                                    int* __restrict__ rowptr, int n) {
    __shared__ int wls[16];
    __shared__ int carry;
    const int tid = threadIdx.x, lane = tid & 63, wid = tid >> 6;
    if (tid == 0) { carry = 0; rowptr[0] = 0; }
    __syncthreads();
    for (int base = 0; base < n; base += 1024) {
        int i = base + tid;
        int v = (i < n) ? cnt[i] : 0;
        int sc = v;
        for (int off = 1; off < 64; off <<= 1) {
            int t = __shfl_up(sc, off);
            if (lane >= off) sc += t;
        }
        if (lane == 63) wls[wid] = sc;
        __syncthreads();
        if (tid == 0) {
            int run = carry;
            for (int w2 = 0; w2 < 16; ++w2) { int t = wls[w2]; wls[w2] = run; run += t; }
            carry = run;
        }
        __syncthreads();
        if (i < n) rowptr[i + 1] = wls[wid] + sc;
        __syncthreads();
    }
}

__global__ __launch_bounds__(256) void fill_kernel(const int* __restrict__ src,
                                                   const int* __restrict__ dst,
                                                   const float* __restrict__ attr,
                                                   const int* __restrict__ rowptr,
                                                   int* __restrict__ tmp,
                                                   int* __restrict__ src_perm,
                                                   float* __restrict__ attr_perm,
                                                   int* __restrict__ eidp, int E) {
    int e = blockIdx.x * 256 + threadIdx.x;
    if (e < E) {
        int d = dst[e];
        int p = atomicAdd(&tmp[d], 1);
        int pos = rowptr[d] + p;
        src_perm[pos] = src[e];
        attr_perm[pos] = attr[e];
        eidp[pos] = e;
    }
}

// f32 -> packed bf16 pairs (u32), n32 = number of u32 outputs
__global__ __launch_bounds__(256) void cvt_bf16_kernel(const float* __restrict__ in,
                                                       unsigned* __restrict__ outp, int n32) {
    int i = blockIdx.x * 256 + threadIdx.x;
    if (i < n32) {
        float2 v = *(const float2*)&in[(size_t)i * 2];
        outp[i] = pack_bf16_rne(v.x, v.y);
    }
}

// transpose W [128][128] f32 -> Wt [col][k] bf16 (packed u32 pairs along k)
// grid (32, 4): y = which matrix; 32*256 threads = 8192 u32 outputs each
__global__ __launch_bounds__(256) void prepack_kernel(
    const float* __restrict__ W0, const float* __restrict__ W1,
    const float* __restrict__ W2, const float* __restrict__ W3,
    unsigned* __restrict__ wt) {
    const int m = blockIdx.y;
    const float* W = (m == 0) ? W0 : (m == 1) ? W1 : (m == 2) ? W2 : W3;
    int idx = blockIdx.x * 256 + threadIdx.x;   // [0, 8192)
    int c = idx >> 6;          // col
    int kp = idx & 63;         // k pair
    float w0 = W[(size_t)(2 * kp) * 128 + c];
    float w1 = W[(size_t)(2 * kp + 1) * 128 + c];
    wt[(size_t)m * 8192 + (size_t)c * 64 + kp] = pack_bf16_rne(w0, w1);
}

// ---------------------------------------------------------------------------
// MFMA GEMM: OUT = Xb @ W + b, K=128, for 4 matrices (y: 0=q f32, 1=k bf16,
// 2=v bf16, 3=skip f32). Xb bf16 [N][128]; Wt bf16 [matrix][col][k].
// Block: 256 thr = 4 waves, 64 rows; wave w: rows 16w..16w+15, all 128 cols.
// Fragments (guide §3, m89-verified): A lane row=l&15, k=8*(l>>4)+[0..7];
// B lane col=l&15 same k; D lane col=l&15, row=4*(l>>4)+r.
// ---------------------------------------------------------------------------
__global__ __launch_bounds__(256) void gemm_mfma_kernel(
    const unsigned short* __restrict__ Xb, const unsigned short* __restrict__ wt,
    const float* __restrict__ bq, const float* __restrict__ bk,
    const float* __restrict__ bv, const float* __restrict__ bs,
    float* __restrict__ qo, unsigned short* __restrict__ ko,
    unsigned short* __restrict__ vo, float* __restrict__ so, int nrows) {
    const int lane = threadIdx.x & 63;
    const int w = threadIdx.x >> 6;
    const int m = blockIdx.y;
    const int strip = blockIdx.x * 64 + w * 16;
    const int arow = strip + (lane & 15);
    const int arow_c = min(arow, nrows - 1);
    const int kblk = (lane >> 4) * 8;
    const unsigned short* Wm = wt + (size_t)m * 16384;
    const float* bias = (m == 0) ? bq : (m == 1) ? bk : (m == 2) ? bv : bs;

    f32x4 acc[8];
#pragma unroll
    for (int f = 0; f < 8; ++f) acc[f] = (f32x4){0.f, 0.f, 0.f, 0.f};

#pragma unroll
    for (int ks = 0; ks < 4; ++ks) {
        const int k0 = ks * 32 + kblk;
        const short8v a = *(const short8v*)&Xb[(size_t)arow_c * 128 + k0];
#pragma unroll
        for (int f = 0; f < 8; ++f) {
            const short8v b = *(const short8v*)&Wm[(size_t)(f * 16 + (lane & 15)) * 128 + k0];
            acc[f] = __builtin_amdgcn_mfma_f32_16x16x32_bf16(a, b, acc[f], 0, 0, 0);
        }
    }

    const int r0 = strip + (lane >> 4) * 4;
#pragma unroll
    for (int f = 0; f < 8; ++f) {
        const int col = f * 16 + (lane & 15);
        const float bv_ = bias[col];
        if (m == 0 || m == 3) {
            float* OUT = (m == 0) ? qo : so;
#pragma unroll
            for (int r = 0; r < 4; ++r) {
                int row = r0 + r;
                if (row < nrows) OUT[(size_t)row * 128 + col] = acc[f][r] + bv_;
            }
        } else {
            unsigned short* OUT = (m == 1) ? ko : vo;
#pragma unroll
            for (int r = 0; r < 4; ++r) {
                int row = r0 + r;
                if (row < nrows) OUT[(size_t)row * 128 + col] = bf16_rne1(acc[f][r] + bv_);
            }
        }
    }
}

// ---------------------------------------------------------------------------
// Fused node kernel: one wave per node (4 waves/block).
// deg<=64 fast path: logits -> LDS transpose -> per-lane register float4;
// wave-reduce max/sum; alpha written to alpha_out + alds; aggregate v.
// deg>64 fallback: old 3-pass path via alpha_perm.
// Lane layout: lane l owns dims (2l, 2l+1); head h = l>>4.
// ---------------------------------------------------------------------------
__global__ __launch_bounds__(256) void node_fused_kernel(
    const float* __restrict__ qb, const unsigned* __restrict__ kb,
    const unsigned* __restrict__ vb,
    const float* __restrict__ Wev, const float* __restrict__ bev,
    const int* __restrict__ rowptr, const int* __restrict__ src_perm,
    const float* __restrict__ attr_perm, const int* __restrict__ eidp,
    float* __restrict__ alpha_perm, float* __restrict__ alpha_out,
    float* __restrict__ out, int n) {
    __shared__ float alds[4][64][4];
    const int wid = threadIdx.x >> 6;
    const int node = blockIdx.x * 4 + wid;
    const int lane = threadIdx.x & 63;
    if (node >= n) return;
    const int start = rowptr[node], end = rowptr[node + 1];
    const int deg = end - start;
    if (deg == 0) return;  // out keeps skip, no alpha

    const float we0 = Wev[2 * lane], we1 = Wev[2 * lane + 1];
    const float be0 = bev[2 * lane], be1 = bev[2 * lane + 1];
    const float2 qv = *(const float2*)&qb[(size_t)node * 128 + 2 * lane];
    const float scale = 0.17677669529663687f;  // 1/sqrt(32)
    const int h = lane >> 4;

    if (deg <= 64) {
        // ---------------- fast path ----------------
        const bool valid = lane < deg;
        const int j = start + lane;
        const int sj = valid ? src_perm[j] : 0;
        const float aj = valid ? attr_perm[j] : 0.f;

        // pass A: logits -> alds[wid][t][head]
        int t = 0;
        for (; t + 1 < deg; t += 2) {
            const int s0 = __shfl(sj, t), s1 = __shfl(sj, t + 1);
            const float a0 = __shfl(aj, t), a1 = __shfl(aj, t + 1);
            const unsigned u0 = kb[(size_t)s0 * 64 + lane];
            const unsigned u1 = kb[(size_t)s1 * 64 + lane];
            float p0 = qv.x * (__uint_as_float(u0 << 16) + a0 * we0 + be0)
                     + qv.y * (__uint_as_float(u0 & 0xffff0000u) + a0 * we1 + be1);
            float p1 = qv.x * (__uint_as_float(u1 << 16) + a1 * we0 + be0)
                     + qv.y * (__uint_as_float(u1 & 0xffff0000u) + a1 * we1 + be1);
#pragma unroll
            for (int off = 1; off < 16; off <<= 1) {
                p0 += __shfl_xor(p0, off);
                p1 += __shfl_xor(p1, off);
            }
            if ((lane & 15) == 0) {
                alds[wid][t][h] = p0 * scale;
                alds[wid][t + 1][h] = p1 * scale;
            }
        }
        if (t < deg) {
            const int s0 = __shfl(sj, t);
            const float a0 = __shfl(aj, t);
            const unsigned u0 = kb[(size_t)s0 * 64 + lane];
            float p0 = qv.x * (__uint_as_float(u0 << 16) + a0 * we0 + be0)
                     + qv.y * (__uint_as_float(u0 & 0xffff0000u) + a0 * we1 + be1);
#pragma unroll
            for (int off = 1; off < 16; off <<= 1) p0 += __shfl_xor(p0, off);
            if ((lane & 15) == 0) alds[wid][t][h] = p0 * scale;
        }

        // transpose: lane j owns edge j's 4 head-logits in registers
        float4 lg = valid ? *(const float4*)&alds[wid][lane][0]
                          : make_float4(-1e30f, -1e30f, -1e30f, -1e30f);
        float4 mx = lg;
#pragma unroll
        for (int off = 1; off < 64; off <<= 1) {
            mx.x = fmaxf(mx.x, __shfl_xor(mx.x, off));
            mx.y = fmaxf(mx.y, __shfl_xor(mx.y, off));
            mx.z = fmaxf(mx.z, __shfl_xor(mx.z, off));
            mx.w = fmaxf(mx.w, __shfl_xor(mx.w, off));
        }
        float4 ev;
        ev.x = __expf(lg.x - mx.x); ev.y = __expf(lg.y - mx.y);
        ev.z = __expf(lg.z - mx.z); ev.w = __expf(lg.w - mx.w);
        float4 s4 = ev;
#pragma unroll
        for (int off = 1; off < 64; off <<= 1) {
            s4.x += __shfl_xor(s4.x, off); s4.y += __shfl_xor(s4.y, off);
            s4.z += __shfl_xor(s4.z, off); s4.w += __shfl_xor(s4.w, off);
        }
        float4 al;
        al.x = ev.x / (s4.x + 1e-16f); al.y = ev.y / (s4.y + 1e-16f);
        al.z = ev.z / (s4.z + 1e-16f); al.w = ev.w / (s4.w + 1e-16f);
        if (valid) *(float4*)&alpha_out[(size_t)eidp[j] * 4] = al;
        *(float4*)&alds[wid][lane][0] = al;

        // pass C: aggregate v weighted by alpha (broadcast reads from alds)
        float acc0 = 0.f, acc1 = 0.f;
        t = 0;
        for (; t + 1 < deg; t += 2) {
            const int s0 = __shfl(sj, t), s1 = __shfl(sj, t + 1);
            const float a0 = __shfl(aj, t), a1 = __shfl(aj, t + 1);
            const float w0 = alds[wid][t][h];
            const float w1 = alds[wid][t + 1][h];
            const unsigned u0 = vb[(size_t)s0 * 64 + lane];
            const unsigned u1 = vb[(size_t)s1 * 64 + lane];
            acc0 += w0 * (__uint_as_float(u0 << 16) + a0 * we0 + be0)
                  + w1 * (__uint_as_float(u1 << 16) + a1 * we0 + be0);
            acc1 += w0 * (__uint_as_float(u0 & 0xffff0000u) + a0 * we1 + be1)
                  + w1 * (__uint_as_float(u1 & 0xffff0000u) + a1 * we1 + be1);
        }
        if (t < deg) {
            const int s0 = __shfl(sj, t);
            const float a0 = __shfl(aj, t);
            const float w0 = alds[wid][t][h];
            const unsigned u0 = vb[(size_t)s0 * 64 + lane];
            acc0 += w0 * (__uint_as_float(u0 << 16) + a0 * we0 + be0);
            acc1 += w0 * (__uint_as_float(u0 & 0xffff0000u) + a0 * we1 + be1);
        }
        float2 o = *(float2*)&out[(size_t)node * 128 + 2 * lane];
        o.x += acc0; o.y += acc1;
        *(float2*)&out[(size_t)node * 128 + 2 * lane] = o;
        return;
    }

    // ---------------- fallback: 3-pass via alpha_perm (deg > 64) ----------------
    float mh = -1e30f;
    for (int c0 = start; c0 < end; c0 += 64) {
        const int nc = min(64, end - c0);
        const int sj = (lane < nc) ? src_perm[c0 + lane] : 0;
        const float aj = (lane < nc) ? attr_perm[c0 + lane] : 0.f;
        int t = 0;
        for (; t + 1 < nc; t += 2) {
            const int s0 = __shfl(sj, t), s1 = __shfl(sj, t + 1);
            const float a0 = __shfl(aj, t), a1 = __shfl(aj, t + 1);
            const unsigned u0 = kb[(size_t)s0 * 64 + lane];
            const unsigned u1 = kb[(size_t)s1 * 64 + lane];
            float p0 = qv.x * (__uint_as_float(u0 << 16) + a0 * we0 + be0)
                     + qv.y * (__uint_as_float(u0 & 0xffff0000u) + a0 * we1 + be1);
            float p1 = qv.x * (__uint_as_float(u1 << 16) + a1 * we0 + be0)
                     + qv.y * (__uint_as_float(u1 & 0xffff0000u) + a1 * we1 + be1);
#pragma unroll
            for (int off = 1; off < 16; off <<= 1) {
                p0 += __shfl_xor(p0, off);
                p1 += __shfl_xor(p1, off);
            }
            p0 *= scale; p1 *= scale;
            mh = fmaxf(mh, fmaxf(p0, p1));
            if ((lane & 15) == 0) {
                alpha_perm[(size_t)(c0 + t) * 4 + h] = p0;
                alpha_perm[(size_t)(c0 + t + 1) * 4 + h] = p1;
            }
        }
        if (t < nc) {
            const int s0 = __shfl(sj, t);
            const float a0 = __shfl(aj, t);
            const unsigned u0 = kb[(size_t)s0 * 64 + lane];
            float p0 = qv.x * (__uint_as_float(u0 << 16) + a0 * we0 + be0)
                     + qv.y * (__uint_as_float(u0 & 0xffff0000u) + a0 * we1 + be1);
#pragma unroll
            for (int off = 1; off < 16; off <<= 1) p0 += __shfl_xor(p0, off);
            p0 *= scale;
            mh = fmaxf(mh, p0);
            if ((lane & 15) == 0) alpha_perm[(size_t)(c0 + t) * 4 + h] = p0;
        }
    }
    const float m0 = __shfl(mh, 0), m1 = __shfl(mh, 16);
    const float m2 = __shfl(mh, 32), m3 = __shfl(mh, 48);

    float4 s4 = make_float4(0.f, 0.f, 0.f, 0.f);
    for (int c0 = start; c0 < end; c0 += 64) {
        const int j = c0 + lane;
        if (j < end) {
            float4 lg = *(const float4*)&alpha_perm[(size_t)j * 4];
            lg.x = __expf(lg.x - m0); lg.y = __expf(lg.y - m1);
            lg.z = __expf(lg.z - m2); lg.w = __expf(lg.w - m3);
            *(float4*)&alpha_perm[(size_t)j * 4] = lg;
            s4.x += lg.x; s4.y += lg.y; s4.z += lg.z; s4.w += lg.w;
        }
    }
#pragma unroll
    for (int off = 1; off < 64; off <<= 1) {
        s4.x += __shfl_xor(s4.x, off); s4.y += __shfl_xor(s4.y, off);
        s4.z += __shfl_xor(s4.z, off); s4.w += __shfl_xor(s4.w, off);
    }
    const float i0 = 1.f / (s4.x + 1e-16f), i1 = 1.f / (s4.y + 1e-16f);
    const float i2 = 1.f / (s4.z + 1e-16f), i3 = 1.f / (s4.w + 1e-16f);

    float acc0 = 0.f, acc1 = 0.f;
    for (int c0 = start; c0 < end; c0 += 64) {
        const int nc = min(64, end - c0);
        const int j = c0 + lane;
        if (lane < nc) {
            float4 ex = *(const float4*)&alpha_perm[(size_t)j * 4];
            float4 al;
            al.x = ex.x * i0; al.y = ex.y * i1; al.z = ex.z * i2; al.w = ex.w * i3;
            *(float4*)&alpha_out[(size_t)eidp[j] * 4] = al;
            *(float4*)&alds[wid][lane][0] = al;
        }
        const int sj = (lane < nc) ? src_perm[j] : 0;
        const float aj = (lane < nc) ? attr_perm[j] : 0.f;
        int t = 0;
        for (; t + 1 < nc; t += 2) {
            const int s0 = __shfl(sj, t), s1 = __shfl(sj, t + 1);
            const float a0 = __shfl(aj, t), a1 = __shfl(aj, t + 1);
            const float w0 = alds[wid][t][h];
            const float w1 = alds[wid][t + 1][h];
            const unsigned u0 = vb[(size_t)s0 * 64 + lane];
            const unsigned u1 = vb[(size_t)s1 * 64 + lane];
            acc0 += w0 * (__uint_as_float(u0 << 16) + a0 * we0 + be0)
                  + w1 * (__uint_as_float(u1 << 16) + a1 * we0 + be0);
            acc1 += w0 * (__uint_as_float(u0 & 0xffff0000u) + a0 * we1 + be1)
                  + w1 * (__uint_as_float(u1 & 0xffff0000u) + a1 * we1 + be1);
        }
        if (t < nc) {
            const int s0 = __shfl(sj, t);
            const float a0 = __shfl(aj, t);
            const float w0 = alds[wid][t][h];
            const unsigned u0 = vb[(size_t)s0 * 64 + lane];
            acc0 += w0 * (__uint_as_float(u0 << 16) + a0 * we0 + be0);
            acc1 += w0 * (__uint_as_float(u0 & 0xffff0000u) + a0 * we1 + be1);
        }
    }
    float2 o = *(float2*)&out[(size_t)node * 128 + 2 * lane];
    o.x += acc0; o.y += acc1;
    *(float2*)&out[(size_t)node * 128 + 2 * lane] = o;
}

// LN+ReLU: read f32 h, write packed bf16 (u32 pairs) for the next GEMM.
// lane owns dims (2l, 2l+1).
__global__ __launch_bounds__(256) void ln_relu_kernel(const float* __restrict__ hin,
                                                      unsigned* __restrict__ hb,
                                                      const float* __restrict__ g,
                                                      const float* __restrict__ b, int n) {
    const int row = (blockIdx.x * 256 + threadIdx.x) >> 6;
    const int lane = threadIdx.x & 63;
    if (row >= n) return;
    const float2 xv = *(const float2*)&hin[(size_t)row * 128 + 2 * lane];
    float s = xv.x + xv.y;
#pragma unroll
    for (int off = 1; off < 64; off <<= 1) s += __shfl_xor(s, off);
    const float mu = s * (1.f / 128.f);
    const float d0 = xv.x - mu, d1 = xv.y - mu;
    float vs = d0 * d0 + d1 * d1;
#pragma unroll
    for (int off = 1; off < 64; off <<= 1) vs += __shfl_xor(vs, off);
    const float inv = rsqrtf(vs * (1.f / 128.f) + 1e-5f);
    const float2 gv = *(const float2*)&g[2 * lane];
    const float2 bv = *(const float2*)&b[2 * lane];
    const float n0 = fmaxf(d0 * inv * gv.x + bv.x, 0.f);
    const float n1 = fmaxf(d1 * inv * gv.y + bv.y, 0.f);
    hb[(size_t)row * 64 + lane] = pack_bf16_rne(n0, n1);
}

// pool: one block per 32 rows, 128 threads (one per column); batch sorted
__global__ __launch_bounds__(128) void pool_kernel(const float* __restrict__ z,
                                                   const int* __restrict__ batch,
                                                   float* __restrict__ pool,
                                                   int* __restrict__ gcnt, int n) {
    const int c = threadIdx.x;
    const int row0 = blockIdx.x * 32;
    if (row0 >= n) return;
    const int rend = min(row0 + 32, n);
    int cur = batch[row0];
    float acc = 0.f;
    int run = 0;
    for (int r = row0; r < rend; ++r) {
        const int g = batch[r];
        if (g != cur) {
            atomicAdd(&pool[cur * 128 + c], acc);
            if (c == 0) atomicAdd(&gcnt[cur], run);
            acc = 0.f; run = 0; cur = g;
        }
        acc += z[(size_t)r * 128 + c];
        ++run;
    }
    atomicAdd(&pool[cur * 128 + c], acc);
    if (c == 0) atomicAdd(&gcnt[cur], run);
}

__global__ __launch_bounds__(128) void classifier_kernel(
    const float* __restrict__ pool, const int* __restrict__ gcnt,
    const int* __restrict__ batch,
    const float* __restrict__ fc1_w, const float* __restrict__ fc1_b,
    const float* __restrict__ cg, const float* __restrict__ cbv,
    const float* __restrict__ fc2_w, const float* __restrict__ fc2_b,
    float* __restrict__ zsel, float* __restrict__ probs) {
    __shared__ float zp[8][128];
    __shared__ float hc[8][128];
    __shared__ float red[2];
    __shared__ float lgt[8][10];
    const int c = threadIdx.x;
    const int lane = c & 63, wid = c >> 6;
#pragma unroll
    for (int g = 0; g < 8; ++g)
        zp[g][c] = pool[g * 128 + c] / fmaxf((float)gcnt[g], 1.f);
    __syncthreads();
    zsel[c] = zp[batch[0]][c];

    float acc[8];
#pragma unroll
    for (int g = 0; g < 8; ++g) acc[g] = fc1_b[c];
    for (int k = 0; k < 128; ++k) {
        const float w = fc1_w[k * 128 + c];
#pragma unroll
        for (int g = 0; g < 8; ++g) acc[g] += zp[g][k] * w;
    }
#pragma unroll
    for (int g = 0; g < 8; ++g) {
        float s = acc[g];
        for (int off = 1; off < 64; off <<= 1) s += __shfl_xor(s, off);
        if (lane == 0) red[wid] = s;
        __syncthreads();
        const float mu = (red[0] + red[1]) * (1.f / 128.f);
        __syncthreads();
        const float d = acc[g] - mu;
        float s2 = d * d;
        for (int off = 1; off < 64; off <<= 1) s2 += __shfl_xor(s2, off);
        if (lane == 0) red[wid] = s2;
        __syncthreads();
        const float var = (red[0] + red[1]) * (1.f / 128.f);
        __syncthreads();
        hc[g][c] = fmaxf(d * rsqrtf(var + 1e-5f) * cg[c] + cbv[c], 0.f);
    }
    __syncthreads();
    if (c < 80) {
        const int g = c / 10, j = c - g * 10;
        float s = fc2_b[j];
        for (int k = 0; k < 128; ++k) s += hc[g][k] * fc2_w[k * 10 + j];
        lgt[g][j] = s;
    }
    __syncthreads();
    if (c < 8) {
        float mx = -1e30f;
#pragma unroll
        for (int j = 0; j < 10; ++j) mx = fmaxf(mx, lgt[c][j]);
        float ex[10];
        float sum = 0.f;
#pragma unroll
        for (int j = 0; j < 10; ++j) { ex[j] = expf(lgt[c][j] - mx); sum += ex[j]; }
#pragma unroll
        for (int j = 0; j < 10; ++j) probs[c * 10 + j] = ex[j] / sum;
    }
}

// ---------------------------------------------------------------------------

extern "C" void kernel_launch(void* const* d_in, const int* in_sizes, int n_in,
                              void* d_out, int out_size, void* d_ws, size_t ws_size,
                              hipStream_t stream) {
    const float* x = (const float*)d_in[0];
    const int* edge_index = (const int*)d_in[1];
    const float* attr = (const float*)d_in[2];
    const int* batch = (const int*)d_in[3];
    const int N = in_sizes[0] / 128;
    const int E = in_sizes[2];
    const int* src = edge_index;
    const int* dst = edge_index + E;

    const float *Wq[3], *Wk[3], *Wv[3], *We[3], *Ws[3];
    const float *bq[3], *bk[3], *bv[3], *be[3], *bs[3];
    int idx = 4;
    for (int l = 0; l < 3; ++l) {
        Wq[l] = (const float*)d_in[idx++];
        Wk[l] = (const float*)d_in[idx++];
        Wv[l] = (const float*)d_in[idx++];
        We[l] = (const float*)d_in[idx++];
        Ws[l] = (const float*)d_in[idx++];
        bq[l] = (const float*)d_in[idx++];
        bk[l] = (const float*)d_in[idx++];
        bv[l] = (const float*)d_in[idx++];
        be[l] = (const float*)d_in[idx++];
        bs[l] = (const float*)d_in[idx++];
    }
    const float* ln_g[2] = {(const float*)d_in[34], (const float*)d_in[36]};
    const float* ln_b[2] = {(const float*)d_in[35], (const float*)d_in[37]};
    const float* fc1_w = (const float*)d_in[38];
    const float* fc1_b = (const float*)d_in[39];
    const float* cln_g = (const float*)d_in[40];
    const float* cln_b = (const float*)d_in[41];
    const float* fc2_w = (const float*)d_in[42];
    const float* fc2_b = (const float*)d_in[43];
    const int C = in_sizes[43];

    float* out = (float*)d_out;
    float* z_out = out;
    float* zsel_out = out + (size_t)N * 128;
    float* probs_out = zsel_out + 128;
    const int GC = out_size - N * 128 - 128 - 3 * E * 4;
    const int G = GC / C;  // = 8
    float* alpha_out[3];
    alpha_out[0] = probs_out + GC;
    alpha_out[1] = alpha_out[0] + (size_t)E * 4;
    alpha_out[2] = alpha_out[1] + (size_t)E * 4;

    // workspace layout
    char* p = (char*)d_ws;
    auto alloc = [&](size_t bytes) {
        void* r = (void*)p;
        p += (bytes + 255) & ~(size_t)255;
        return r;
    };
    float* qb = (float*)alloc((size_t)N * 128 * 4);
    unsigned* kb = (unsigned*)alloc((size_t)N * 64 * 4);
    unsigned* vb = (unsigned*)alloc((size_t)N * 64 * 4);
    float* hA = (float*)alloc((size_t)N * 128 * 4);
    float* hB = (float*)alloc((size_t)N * 128 * 4);
    unsigned* xb = (unsigned*)alloc((size_t)N * 64 * 4);   // bf16 activations (layer input)
    unsigned* hb = (unsigned*)alloc((size_t)N * 64 * 4);   // bf16 LN output
    unsigned* wt = (unsigned*)alloc((size_t)12 * 8192 * 4);  // 12 transposed bf16 W
    int* counts = (int*)alloc((size_t)N * 4);
    int* rowptr = (int*)alloc((size_t)(N + 1) * 4);
    int* cnt2 = (int*)alloc((size_t)N * 4);
    int* src_perm = (int*)alloc((size_t)E * 4);
    float* attr_perm = (float*)alloc((size_t)E * 4);
    int* eidp = (int*)alloc((size_t)E * 4);
    float* alpha_perm = (float*)alloc((size_t)E * 4 * 4);
    float* pool = (float*)alloc((size_t)G * 128 * 4);
    int* gcnt = (int*)alloc((size_t)G * 4);

    hipMemsetAsync(counts, 0, (size_t)N * 4, stream);
    hipMemsetAsync(cnt2, 0, (size_t)N * 4, stream);
    hipMemsetAsync(pool, 0, (size_t)G * 128 * 4, stream);
    hipMemsetAsync(gcnt, 0, (size_t)G * 4, stream);

    // CSR over dst (+ permuted src/attr/eid)
    hist_kernel<<<(E + 255) / 256, 256, 0, stream>>>(dst, counts, E);
    scan_kernel<<<1, 1024, 0, stream>>>(counts, rowptr, N);
    fill_kernel<<<(E + 255) / 256, 256, 0, stream>>>(src, dst, attr, rowptr, cnt2,
                                                     src_perm, attr_perm, eidp, E);

    // activations -> bf16; weights -> transposed bf16
    cvt_bf16_kernel<<<(N * 64 + 255) / 256, 256, 0, stream>>>(x, xb, N * 64);
    for (int l = 0; l < 3; ++l)
        prepack_kernel<<<dim3(32, 4), 256, 0, stream>>>(Wq[l], Wk[l], Wv[l], Ws[l],
                                                        wt + (size_t)l * 4 * 8192);

    for (int l = 0; l < 3; ++l) {
        float* OUTl = (l == 0) ? hA : (l == 1) ? hB : z_out;
        const unsigned short* Xin = (const unsigned short*)((l == 0) ? xb : hb);
        gemm_mfma_kernel<<<dim3((N + 63) / 64, 4), 256, 0, stream>>>(
            Xin, (const unsigned short*)(wt + (size_t)l * 4 * 8192),
            bq[l], bk[l], bv[l], bs[l],
            qb, (unsigned short*)kb, (unsigned short*)vb, OUTl, N);
        node_fused_kernel<<<(N + 3) / 4, 256, 0, stream>>>(
            qb, kb, vb, We[l], be[l], rowptr, src_perm, attr_perm, eidp,
            alpha_perm, alpha_out[l], OUTl, N);
        if (l < 2)
            ln_relu_kernel<<<((N + 3) / 4), 256, 0, stream>>>(OUTl, hb, ln_g[l], ln_b[l], N);
    }

    pool_kernel<<<(N + 31) / 32, 128, 0, stream>>>(z_out, batch, pool, gcnt, N);
    classifier_kernel<<<1, 128, 0, stream>>>(pool, gcnt, batch, fc1_w, fc1_b,
                                             cln_g, cln_b, fc2_w, fc2_b,
                                             zsel_out, probs_out);
}

// Round 8
// 501.751 us; speedup vs baseline: 1.6472x; 1.0441x over previous
//
#include <hip/hip_runtime.h>

// ---------------------------------------------------------------------------
// GraphVAE (3x TransformerConv + LN/ReLU + mean-pool + classifier).
// Round 7 (resubmit): factorized edge math (qwe/qbe precompute, sa postapply),
// 4x unrolled gathers, LN fused into node epilogue, parallel 3-kernel scan,
// merged prepack. bf16 MFMA GEMMs; bf16 k/v.
// ---------------------------------------------------------------------------

typedef short short8v __attribute__((ext_vector_type(8)));
typedef float f32x4 __attribute__((ext_vector_type(4)));

__device__ __forceinline__ unsigned pack_bf16_rne(float a, float b) {
    unsigned ua = __float_as_uint(a);
    ua += 0x7fffu + ((ua >> 16) & 1u);
    unsigned ub = __float_as_uint(b);
    ub += 0x7fffu + ((ub >> 16) & 1u);
    return (ua >> 16) | (ub & 0xffff0000u);
}

__device__ __forceinline__ unsigned short bf16_rne1(float a) {
    unsigned u = __float_as_uint(a);
    u += 0x7fffu + ((u >> 16) & 1u);
    return (unsigned short)(u >> 16);
}

__device__ __forceinline__ float blo(unsigned u) { return __uint_as_float(u << 16); }
__device__ __forceinline__ float bhi(unsigned u) { return __uint_as_float(u & 0xffff0000u); }

__global__ __launch_bounds__(256) void hist_kernel(const int* __restrict__ dst,
                                                   int* __restrict__ cnt, int E) {
    int e = blockIdx.x * 256 + threadIdx.x;
    if (e < E) atomicAdd(&cnt[dst[e]], 1);
}

// ---- parallel scan: per-block reduce -> single-block scan -> fill ----
__global__ __launch_bounds__(256) void blk_reduce_kernel(const int* __restrict__ cnt,
                                                         int* __restrict__ bsum, int n) {
    __shared__ int ws[4];
    const int i = blockIdx.x * 256 + threadIdx.x;
    const int lane = threadIdx.x & 63, wid = threadIdx.x >> 6;
    int v = (i < n) ? cnt[i] : 0;
#pragma unroll
    for (int off = 1; off < 64; off <<= 1) v += __shfl_xor(v, off);
    if (lane == 0) ws[wid] = v;
    __syncthreads();
    if (threadIdx.x == 0) bsum[blockIdx.x] = ws[0] + ws[1] + ws[2] + ws[3];
}

// single-pass exclusive scan of bsum (nb <= 1024), in place
__global__ __launch_bounds__(1024) void blk_scan_kernel(int* __restrict__ bsum, int nb) {
    __shared__ int wls[16];
    const int tid = threadIdx.x, lane = tid & 63, wid = tid >> 6;
    int v = (tid < nb) ? bsum[tid] : 0;
    int sc = v;
#pragma unroll
    for (int off = 1; off < 64; off <<= 1) {
        int t = __shfl_up(sc, off);
        if (lane >= off) sc += t;
    }
    if (lane == 63) wls[wid] = sc;
    __syncthreads();
    if (tid == 0) {
        int run = 0;
        for (int w = 0; w < 16; ++w) { int t = wls[w]; wls[w] = run; run += t; }
    }
    __syncthreads();
    if (tid < nb) bsum[tid] = wls[wid] + sc - v;  // exclusive
}

__global__ __launch_bounds__(256) void rowptr_fill_kernel(const int* __restrict__ cnt,
                                                          const int* __restrict__ boff,
                                                          int* __restrict__ rowptr, int n) {
    __shared__ int wls[4];
    const int i = blockIdx.x * 256 + threadIdx.x;
    const int lane = threadIdx.x & 63, wid = threadIdx.x >> 6;
    int v = (i < n) ? cnt[i] : 0;
    int sc = v;
#pragma unroll
    for (int off = 1; off < 64; off <<= 1) {
        int t = __shfl_up(sc, off);
        if (lane >= off) sc += t;
    }
    if (lane == 63) wls[wid] = sc;
    __syncthreads();
    int add = boff[blockIdx.x];
    for (int w = 0; w < wid; ++w) add += wls[w];
    if (i < n) rowptr[i + 1] = sc + add;
    if (i == 0) rowptr[0] = 0;
}

__global__ __launch_bounds__(256) void fill_kernel(const int* __restrict__ src,
                                                   const int* __restrict__ dst,
                                                   const float* __restrict__ attr,
                                                   const int* __restrict__ rowptr,
                                                   int* __restrict__ tmp,
                                                   int* __restrict__ src_perm,
                                                   float* __restrict__ attr_perm,
                                                   int* __restrict__ eidp, int E) {
    int e = blockIdx.x * 256 + threadIdx.x;
    if (e < E) {
        int d = dst[e];
        int p = atomicAdd(&tmp[d], 1);
        int pos = rowptr[d] + p;
        src_perm[pos] = src[e];
        attr_perm[pos] = attr[e];
        eidp[pos] = e;
    }
}

// f32 -> packed bf16 pairs (u32)
__global__ __launch_bounds__(256) void cvt_bf16_kernel(const float* __restrict__ in,
                                                       unsigned* __restrict__ outp, int n32) {
    int i = blockIdx.x * 256 + threadIdx.x;
    if (i < n32) {
        float2 v = *(const float2*)&in[(size_t)i * 2];
        outp[i] = pack_bf16_rne(v.x, v.y);
    }
}

// all 12 weight matrices -> transposed bf16 [m][col][k], one launch
struct W12 { const float* p[12]; };
__global__ __launch_bounds__(256) void prepack_all_kernel(W12 ws, unsigned* __restrict__ wt) {
    const int m = blockIdx.y;
    const float* W = ws.p[m];
    int idx = blockIdx.x * 256 + threadIdx.x;   // [0, 8192)
    int c = idx >> 6;
    int kp = idx & 63;
    wt[(size_t)m * 8192 + (size_t)c * 64 + kp] =
        pack_bf16_rne(W[(size_t)(2 * kp) * 128 + c], W[(size_t)(2 * kp + 1) * 128 + c]);
}

// ---------------------------------------------------------------------------
// MFMA GEMM: OUT = Xb @ W + b, K=128 (y: 0=q f32, 1=k bf16, 2=v bf16, 3=skip f32)
// ---------------------------------------------------------------------------
__global__ __launch_bounds__(256) void gemm_mfma_kernel(
    const unsigned short* __restrict__ Xb, const unsigned short* __restrict__ wt,
    const float* __restrict__ bq, const float* __restrict__ bk,
    const float* __restrict__ bv, const float* __restrict__ bs,
    float* __restrict__ qo, unsigned short* __restrict__ ko,
    unsigned short* __restrict__ vo, float* __restrict__ so, int nrows) {
    const int lane = threadIdx.x & 63;
    const int w = threadIdx.x >> 6;
    const int m = blockIdx.y;
    const int strip = blockIdx.x * 64 + w * 16;
    const int arow = strip + (lane & 15);
    const int arow_c = min(arow, nrows - 1);
    const int kblk = (lane >> 4) * 8;
    const unsigned short* Wm = wt + (size_t)m * 16384;
    const float* bias = (m == 0) ? bq : (m == 1) ? bk : (m == 2) ? bv : bs;

    f32x4 acc[8];
#pragma unroll
    for (int f = 0; f < 8; ++f) acc[f] = (f32x4){0.f, 0.f, 0.f, 0.f};

#pragma unroll
    for (int ks = 0; ks < 4; ++ks) {
        const int k0 = ks * 32 + kblk;
        const short8v a = *(const short8v*)&Xb[(size_t)arow_c * 128 + k0];
#pragma unroll
        for (int f = 0; f < 8; ++f) {
            const short8v b = *(const short8v*)&Wm[(size_t)(f * 16 + (lane & 15)) * 128 + k0];
            acc[f] = __builtin_amdgcn_mfma_f32_16x16x32_bf16(a, b, acc[f], 0, 0, 0);
        }
    }

    const int r0 = strip + (lane >> 4) * 4;
#pragma unroll
    for (int f = 0; f < 8; ++f) {
        const int col = f * 16 + (lane & 15);
        const float bv_ = bias[col];
        if (m == 0 || m == 3) {
            float* OUT = (m == 0) ? qo : so;
#pragma unroll
            for (int r = 0; r < 4; ++r) {
                int row = r0 + r;
                if (row < nrows) OUT[(size_t)row * 128 + col] = acc[f][r] + bv_;
            }
        } else {
            unsigned short* OUT = (m == 1) ? ko : vo;
#pragma unroll
            for (int r = 0; r < 4; ++r) {
                int row = r0 + r;
                if (row < nrows) OUT[(size_t)row * 128 + col] = bf16_rne1(acc[f][r] + bv_);
            }
        }
    }
}

// ---------------------------------------------------------------------------
// Fused node kernel (one wave per node, 4 waves/block):
//   factorized: logit = q.k + a*(q.we) + q.be ; out = skip + S(a v) + sa*we + be
//   deg<=64 fast path fully in registers; deg>64 fallback via alpha_perm.
//   Epilogue: LN+ReLU -> bf16 hb (layers 0,1) or f32 z (layer 2).
// Lane layout: lane l owns dims (2l, 2l+1); head h = l>>4.
// ---------------------------------------------------------------------------
__global__ __launch_bounds__(256) void node_fused_kernel(
    const float* __restrict__ qb, const unsigned* __restrict__ kb,
    const unsigned* __restrict__ vb,
    const float* __restrict__ Wev, const float* __restrict__ bev,
    const int* __restrict__ rowptr, const int* __restrict__ src_perm,
    const float* __restrict__ attr_perm, const int* __restrict__ eidp,
    float* __restrict__ alpha_perm, float* __restrict__ alpha_out,
    const float* __restrict__ skip, float* __restrict__ zout,
    unsigned* __restrict__ hbout,
    const float* __restrict__ lng, const float* __restrict__ lnb,
    int do_ln, int n) {
    __shared__ float alds[4][64][4];
    const int wid = threadIdx.x >> 6;
    const int node = blockIdx.x * 4 + wid;
    const int lane = threadIdx.x & 63;
    if (node >= n) return;
    const int start = rowptr[node], end = rowptr[node + 1];
    const int deg = end - start;
    const int h = lane >> 4;
    const float we0 = Wev[2 * lane], we1 = Wev[2 * lane + 1];
    const float be0 = bev[2 * lane], be1 = bev[2 * lane + 1];
    const float2 qv = *(const float2*)&qb[(size_t)node * 128 + 2 * lane];
    const float scale = 0.17677669529663687f;  // 1/sqrt(32)
    const bool fastp = (deg <= 64);

    float acc0 = 0.f, acc1 = 0.f, sa = 0.f;

    if (deg > 0 && fastp) {
        // pass 0: per-head q.we, q.be (all lanes get head-local sums)
        float pw = qv.x * we0 + qv.y * we1;
        float pb = qv.x * be0 + qv.y * be1;
#pragma unroll
        for (int off = 1; off < 16; off <<= 1) {
            pw += __shfl_xor(pw, off);
            pb += __shfl_xor(pb, off);
        }

        const bool valid = lane < deg;
        const int j = start + lane;
        const int sj = valid ? src_perm[j] : 0;
        const float aj = valid ? attr_perm[j] : 0.f;

        // ---- pass A: logits (q.k only), 4 edges in flight ----
        int t = 0;
        for (; t + 3 < deg; t += 4) {
            const int s0 = __shfl(sj, t), s1 = __shfl(sj, t + 1);
            const int s2 = __shfl(sj, t + 2), s3 = __shfl(sj, t + 3);
            const float a0 = __shfl(aj, t), a1 = __shfl(aj, t + 1);
            const float a2 = __shfl(aj, t + 2), a3 = __shfl(aj, t + 3);
            const unsigned u0 = kb[(size_t)s0 * 64 + lane];
            const unsigned u1 = kb[(size_t)s1 * 64 + lane];
            const unsigned u2 = kb[(size_t)s2 * 64 + lane];
            const unsigned u3 = kb[(size_t)s3 * 64 + lane];
            float p0 = qv.x * blo(u0) + qv.y * bhi(u0);
            float p1 = qv.x * blo(u1) + qv.y * bhi(u1);
            float p2 = qv.x * blo(u2) + qv.y * bhi(u2);
            float p3 = qv.x * blo(u3) + qv.y * bhi(u3);
#pragma unroll
            for (int off = 1; off < 16; off <<= 1) {
                p0 += __shfl_xor(p0, off); p1 += __shfl_xor(p1, off);
                p2 += __shfl_xor(p2, off); p3 += __shfl_xor(p3, off);
            }
            if ((lane & 15) == 0) {
                alds[wid][t + 0][h] = (p0 + a0 * pw + pb) * scale;
                alds[wid][t + 1][h] = (p1 + a1 * pw + pb) * scale;
                alds[wid][t + 2][h] = (p2 + a2 * pw + pb) * scale;
                alds[wid][t + 3][h] = (p3 + a3 * pw + pb) * scale;
            }
        }
        for (; t < deg; ++t) {
            const int s0 = __shfl(sj, t);
            const float a0 = __shfl(aj, t);
            const unsigned u0 = kb[(size_t)s0 * 64 + lane];
            float p0 = qv.x * blo(u0) + qv.y * bhi(u0);
#pragma unroll
            for (int off = 1; off < 16; off <<= 1) p0 += __shfl_xor(p0, off);
            if ((lane & 15) == 0) alds[wid][t][h] = (p0 + a0 * pw + pb) * scale;
        }

        // ---- softmax (lane j owns edge j's 4 head-logits) ----
        float4 lg = valid ? *(const float4*)&alds[wid][lane][0]
                          : make_float4(-1e30f, -1e30f, -1e30f, -1e30f);
        float4 mx = lg;
#pragma unroll
        for (int off = 1; off < 64; off <<= 1) {
            mx.x = fmaxf(mx.x, __shfl_xor(mx.x, off));
            mx.y = fmaxf(mx.y, __shfl_xor(mx.y, off));
            mx.z = fmaxf(mx.z, __shfl_xor(mx.z, off));
            mx.w = fmaxf(mx.w, __shfl_xor(mx.w, off));
        }
        float4 ev;
        ev.x = __expf(lg.x - mx.x); ev.y = __expf(lg.y - mx.y);
        ev.z = __expf(lg.z - mx.z); ev.w = __expf(lg.w - mx.w);
        float4 s4 = ev;
#pragma unroll
        for (int off = 1; off < 64; off <<= 1) {
            s4.x += __shfl_xor(s4.x, off); s4.y += __shfl_xor(s4.y, off);
            s4.z += __shfl_xor(s4.z, off); s4.w += __shfl_xor(s4.w, off);
        }
        float4 al;
        al.x = ev.x / (s4.x + 1e-16f); al.y = ev.y / (s4.y + 1e-16f);
        al.z = ev.z / (s4.z + 1e-16f); al.w = ev.w / (s4.w + 1e-16f);
        if (valid) *(float4*)&alpha_out[(size_t)eidp[j] * 4] = al;
        *(float4*)&alds[wid][lane][0] = al;

        // ---- pass C: acc += alpha*v ; sa += alpha*a ----
        t = 0;
        for (; t + 3 < deg; t += 4) {
            const int s0 = __shfl(sj, t), s1 = __shfl(sj, t + 1);
            const int s2 = __shfl(sj, t + 2), s3 = __shfl(sj, t + 3);
            const float a0 = __shfl(aj, t), a1 = __shfl(aj, t + 1);
            const float a2 = __shfl(aj, t + 2), a3 = __shfl(aj, t + 3);
            const float w0 = alds[wid][t + 0][h];
            const float w1 = alds[wid][t + 1][h];
            const float w2 = alds[wid][t + 2][h];
            const float w3 = alds[wid][t + 3][h];
            const unsigned u0 = vb[(size_t)s0 * 64 + lane];
            const unsigned u1 = vb[(size_t)s1 * 64 + lane];
            const unsigned u2 = vb[(size_t)s2 * 64 + lane];
            const unsigned u3 = vb[(size_t)s3 * 64 + lane];
            acc0 += w0 * blo(u0) + w1 * blo(u1) + w2 * blo(u2) + w3 * blo(u3);
            acc1 += w0 * bhi(u0) + w1 * bhi(u1) + w2 * bhi(u2) + w3 * bhi(u3);
            sa += w0 * a0 + w1 * a1 + w2 * a2 + w3 * a3;
        }
        for (; t < deg; ++t) {
            const int s0 = __shfl(sj, t);
            const float a0 = __shfl(aj, t);
            const float w0 = alds[wid][t][h];
            const unsigned u0 = vb[(size_t)s0 * 64 + lane];
            acc0 += w0 * blo(u0);
            acc1 += w0 * bhi(u0);
            sa += w0 * a0;
        }
    } else if (deg > 0) {
        // ---------------- fallback (deg > 64): 3-pass via alpha_perm ----------------
        float mh = -1e30f;
        for (int c0 = start; c0 < end; c0 += 64) {
            const int nc = min(64, end - c0);
            const int sj = (lane < nc) ? src_perm[c0 + lane] : 0;
            const float aj = (lane < nc) ? attr_perm[c0 + lane] : 0.f;
            int t = 0;
            for (; t + 1 < nc; t += 2) {
                const int s0 = __shfl(sj, t), s1 = __shfl(sj, t + 1);
                const float a0 = __shfl(aj, t), a1 = __shfl(aj, t + 1);
                const unsigned u0 = kb[(size_t)s0 * 64 + lane];
                const unsigned u1 = kb[(size_t)s1 * 64 + lane];
                float p0 = qv.x * (blo(u0) + a0 * we0 + be0) + qv.y * (bhi(u0) + a0 * we1 + be1);
                float p1 = qv.x * (blo(u1) + a1 * we0 + be0) + qv.y * (bhi(u1) + a1 * we1 + be1);
#pragma unroll
                for (int off = 1; off < 16; off <<= 1) {
                    p0 += __shfl_xor(p0, off);
                    p1 += __shfl_xor(p1, off);
                }
                p0 *= scale; p1 *= scale;
                mh = fmaxf(mh, fmaxf(p0, p1));
                if ((lane & 15) == 0) {
                    alpha_perm[(size_t)(c0 + t) * 4 + h] = p0;
                    alpha_perm[(size_t)(c0 + t + 1) * 4 + h] = p1;
                }
            }
            if (t < nc) {
                const int s0 = __shfl(sj, t);
                const float a0 = __shfl(aj, t);
                const unsigned u0 = kb[(size_t)s0 * 64 + lane];
                float p0 = qv.x * (blo(u0) + a0 * we0 + be0) + qv.y * (bhi(u0) + a0 * we1 + be1);
#pragma unroll
                for (int off = 1; off < 16; off <<= 1) p0 += __shfl_xor(p0, off);
                p0 *= scale;
                mh = fmaxf(mh, p0);
                if ((lane & 15) == 0) alpha_perm[(size_t)(c0 + t) * 4 + h] = p0;
            }
        }
        const float m0 = __shfl(mh, 0), m1 = __shfl(mh, 16);
        const float m2 = __shfl(mh, 32), m3 = __shfl(mh, 48);

        float4 s4 = make_float4(0.f, 0.f, 0.f, 0.f);
        for (int c0 = start; c0 < end; c0 += 64) {
            const int j = c0 + lane;
            if (j < end) {
                float4 lg = *(const float4*)&alpha_perm[(size_t)j * 4];
                lg.x = __expf(lg.x - m0); lg.y = __expf(lg.y - m1);
                lg.z = __expf(lg.z - m2); lg.w = __expf(lg.w - m3);
                *(float4*)&alpha_perm[(size_t)j * 4] = lg;
                s4.x += lg.x; s4.y += lg.y; s4.z += lg.z; s4.w += lg.w;
            }
        }
#pragma unroll
        for (int off = 1; off < 64; off <<= 1) {
            s4.x += __shfl_xor(s4.x, off); s4.y += __shfl_xor(s4.y, off);
            s4.z += __shfl_xor(s4.z, off); s4.w += __shfl_xor(s4.w, off);
        }
        const float i0 = 1.f / (s4.x + 1e-16f), i1 = 1.f / (s4.y + 1e-16f);
        const float i2 = 1.f / (s4.z + 1e-16f), i3 = 1.f / (s4.w + 1e-16f);

        for (int c0 = start; c0 < end; c0 += 64) {
            const int nc = min(64, end - c0);
            const int j = c0 + lane;
            if (lane < nc) {
                float4 ex = *(const float4*)&alpha_perm[(size_t)j * 4];
                float4 al;
                al.x = ex.x * i0; al.y = ex.y * i1; al.z = ex.z * i2; al.w = ex.w * i3;
                *(float4*)&alpha_out[(size_t)eidp[j] * 4] = al;
                *(float4*)&alds[wid][lane][0] = al;
            }
            const int sj = (lane < nc) ? src_perm[j] : 0;
            const float aj = (lane < nc) ? attr_perm[j] : 0.f;
            int t = 0;
            for (; t + 1 < nc; t += 2) {
                const int s0 = __shfl(sj, t), s1 = __shfl(sj, t + 1);
                const float a0 = __shfl(aj, t), a1 = __shfl(aj, t + 1);
                const float w0 = alds[wid][t][h];
                const float w1 = alds[wid][t + 1][h];
                const unsigned u0 = vb[(size_t)s0 * 64 + lane];
                const unsigned u1 = vb[(size_t)s1 * 64 + lane];
                acc0 += w0 * (blo(u0) + a0 * we0 + be0) + w1 * (blo(u1) + a1 * we0 + be0);
                acc1 += w0 * (bhi(u0) + a0 * we1 + be1) + w1 * (bhi(u1) + a1 * we1 + be1);
            }
            if (t < nc) {
                const int s0 = __shfl(sj, t);
                const float a0 = __shfl(aj, t);
                const float w0 = alds[wid][t][h];
                const unsigned u0 = vb[(size_t)s0 * 64 + lane];
                acc0 += w0 * (blo(u0) + a0 * we0 + be0);
                acc1 += w0 * (bhi(u0) + a0 * we1 + be1);
            }
        }
    }

    // ---- epilogue: skip + aggregate (+ sa*we + be for fast path), LN/ReLU ----
    float2 o = *(const float2*)&skip[(size_t)node * 128 + 2 * lane];
    if (deg > 0) {
        if (fastp) {
            o.x += acc0 + sa * we0 + be0;
            o.y += acc1 + sa * we1 + be1;
        } else {
            o.x += acc0;
            o.y += acc1;
        }
    }
    if (do_ln) {
        float s = o.x + o.y;
#pragma unroll
        for (int off = 1; off < 64; off <<= 1) s += __shfl_xor(s, off);
        const float mu = s * (1.f / 128.f);
        const float d0 = o.x - mu, d1 = o.y - mu;
        float vs = d0 * d0 + d1 * d1;
#pragma unroll
        for (int off = 1; off < 64; off <<= 1) vs += __shfl_xor(vs, off);
        const float inv = rsqrtf(vs * (1.f / 128.f) + 1e-5f);
        const float2 gv = *(const float2*)&lng[2 * lane];
        const float2 bv2 = *(const float2*)&lnb[2 * lane];
        const float n0 = fmaxf(d0 * inv * gv.x + bv2.x, 0.f);
        const float n1 = fmaxf(d1 * inv * gv.y + bv2.y, 0.f);
        hbout[(size_t)node * 64 + lane] = pack_bf16_rne(n0, n1);
    } else {
        *(float2*)&zout[(size_t)node * 128 + 2 * lane] = o;
    }
}

// pool: one block per 32 rows, 128 threads (one per column); batch sorted
__global__ __launch_bounds__(128) void pool_kernel(const float* __restrict__ z,
                                                   const int* __restrict__ batch,
                                                   float* __restrict__ pool,
                                                   int* __restrict__ gcnt, int n) {
    const int c = threadIdx.x;
    const int row0 = blockIdx.x * 32;
    if (row0 >= n) return;
    const int rend = min(row0 + 32, n);
    int cur = batch[row0];
    float acc = 0.f;
    int run = 0;
    for (int r = row0; r < rend; ++r) {
        const int g = batch[r];
        if (g != cur) {
            atomicAdd(&pool[cur * 128 + c], acc);
            if (c == 0) atomicAdd(&gcnt[cur], run);
            acc = 0.f; run = 0; cur = g;
        }
        acc += z[(size_t)r * 128 + c];
        ++run;
    }
    atomicAdd(&pool[cur * 128 + c], acc);
    if (c == 0) atomicAdd(&gcnt[cur], run);
}

__global__ __launch_bounds__(128) void classifier_kernel(
    const float* __restrict__ pool, const int* __restrict__ gcnt,
    const int* __restrict__ batch,
    const float* __restrict__ fc1_w, const float* __restrict__ fc1_b,
    const float* __restrict__ cg, const float* __restrict__ cbv,
    const float* __restrict__ fc2_w, const float* __restrict__ fc2_b,
    float* __restrict__ zsel, float* __restrict__ probs) {
    __shared__ float zp[8][128];
    __shared__ float hc[8][128];
    __shared__ float red[2];
    __shared__ float lgt[8][10];
    const int c = threadIdx.x;
    const int lane = c & 63, wid = c >> 6;
#pragma unroll
    for (int g = 0; g < 8; ++g)
        zp[g][c] = pool[g * 128 + c] / fmaxf((float)gcnt[g], 1.f);
    __syncthreads();
    zsel[c] = zp[batch[0]][c];

    float acc[8];
#pragma unroll
    for (int g = 0; g < 8; ++g) acc[g] = fc1_b[c];
    for (int k = 0; k < 128; ++k) {
        const float w = fc1_w[k * 128 + c];
#pragma unroll
        for (int g = 0; g < 8; ++g) acc[g] += zp[g][k] * w;
    }
#pragma unroll
    for (int g = 0; g < 8; ++g) {
        float s = acc[g];
        for (int off = 1; off < 64; off <<= 1) s += __shfl_xor(s, off);
        if (lane == 0) red[wid] = s;
        __syncthreads();
        const float mu = (red[0] + red[1]) * (1.f / 128.f);
        __syncthreads();
        const float d = acc[g] - mu;
        float s2 = d * d;
        for (int off = 1; off < 64; off <<= 1) s2 += __shfl_xor(s2, off);
        if (lane == 0) red[wid] = s2;
        __syncthreads();
        const float var = (red[0] + red[1]) * (1.f / 128.f);
        __syncthreads();
        hc[g][c] = fmaxf(d * rsqrtf(var + 1e-5f) * cg[c] + cbv[c], 0.f);
    }
    __syncthreads();
    if (c < 80) {
        const int g = c / 10, j = c - g * 10;
        float s = fc2_b[j];
        for (int k = 0; k < 128; ++k) s += hc[g][k] * fc2_w[k * 10 + j];
        lgt[g][j] = s;
    }
    __syncthreads();
    if (c < 8) {
        float mx = -1e30f;
#pragma unroll
        for (int j = 0; j < 10; ++j) mx = fmaxf(mx, lgt[c][j]);
        float ex[10];
        float sum = 0.f;
#pragma unroll
        for (int j = 0; j < 10; ++j) { ex[j] = expf(lgt[c][j] - mx); sum += ex[j]; }
#pragma unroll
        for (int j = 0; j < 10; ++j) probs[c * 10 + j] = ex[j] / sum;
    }
}

// ---------------------------------------------------------------------------

extern "C" void kernel_launch(void* const* d_in, const int* in_sizes, int n_in,
                              void* d_out, int out_size, void* d_ws, size_t ws_size,
                              hipStream_t stream) {
    const float* x = (const float*)d_in[0];
    const int* edge_index = (const int*)d_in[1];
    const float* attr = (const float*)d_in[2];
    const int* batch = (const int*)d_in[3];
    const int N = in_sizes[0] / 128;
    const int E = in_sizes[2];
    const int* src = edge_index;
    const int* dst = edge_index + E;

    const float *Wq[3], *Wk[3], *Wv[3], *We[3], *Ws[3];
    const float *bq[3], *bk[3], *bv[3], *be[3], *bs[3];
    int idx = 4;
    for (int l = 0; l < 3; ++l) {
        Wq[l] = (const float*)d_in[idx++];
        Wk[l] = (const float*)d_in[idx++];
        Wv[l] = (const float*)d_in[idx++];
        We[l] = (const float*)d_in[idx++];
        Ws[l] = (const float*)d_in[idx++];
        bq[l] = (const float*)d_in[idx++];
        bk[l] = (const float*)d_in[idx++];
        bv[l] = (const float*)d_in[idx++];
        be[l] = (const float*)d_in[idx++];
        bs[l] = (const float*)d_in[idx++];
    }
    const float* ln_g[2] = {(const float*)d_in[34], (const float*)d_in[36]};
    const float* ln_b[2] = {(const float*)d_in[35], (const float*)d_in[37]};
    const float* fc1_w = (const float*)d_in[38];
    const float* fc1_b = (const float*)d_in[39];
    const float* cln_g = (const float*)d_in[40];
    const float* cln_b = (const float*)d_in[41];
    const float* fc2_w = (const float*)d_in[42];
    const float* fc2_b = (const float*)d_in[43];
    const int C = in_sizes[43];

    float* out = (float*)d_out;
    float* z_out = out;
    float* zsel_out = out + (size_t)N * 128;
    float* probs_out = zsel_out + 128;
    const int GC = out_size - N * 128 - 128 - 3 * E * 4;
    const int G = GC / C;  // = 8
    float* alpha_out[3];
    alpha_out[0] = probs_out + GC;
    alpha_out[1] = alpha_out[0] + (size_t)E * 4;
    alpha_out[2] = alpha_out[1] + (size_t)E * 4;

    // workspace layout
    char* p = (char*)d_ws;
    auto alloc = [&](size_t bytes) {
        void* r = (void*)p;
        p += (bytes + 255) & ~(size_t)255;
        return r;
    };
    float* qb = (float*)alloc((size_t)N * 128 * 4);
    unsigned* kb = (unsigned*)alloc((size_t)N * 64 * 4);
    unsigned* vb = (unsigned*)alloc((size_t)N * 64 * 4);
    float* hA = (float*)alloc((size_t)N * 128 * 4);       // skip buffer (layers 0,1)
    unsigned* xb = (unsigned*)alloc((size_t)N * 64 * 4);  // bf16 x
    unsigned* hb = (unsigned*)alloc((size_t)N * 64 * 4);  // bf16 LN output
    unsigned* wt = (unsigned*)alloc((size_t)12 * 8192 * 4);
    int* counts = (int*)alloc((size_t)N * 4);
    int* rowptr = (int*)alloc((size_t)(N + 1) * 4);
    int* cnt2 = (int*)alloc((size_t)N * 4);
    int* bsum = (int*)alloc((size_t)1024 * 4);
    int* src_perm = (int*)alloc((size_t)E * 4);
    float* attr_perm = (float*)alloc((size_t)E * 4);
    int* eidp = (int*)alloc((size_t)E * 4);
    float* alpha_perm = (float*)alloc((size_t)E * 4 * 4);
    float* pool = (float*)alloc((size_t)G * 128 * 4);
    int* gcnt = (int*)alloc((size_t)G * 4);

    hipMemsetAsync(counts, 0, (size_t)N * 4, stream);
    hipMemsetAsync(cnt2, 0, (size_t)N * 4, stream);
    hipMemsetAsync(pool, 0, (size_t)G * 128 * 4, stream);
    hipMemsetAsync(gcnt, 0, (size_t)G * 4, stream);

    const int nb = (N + 255) / 256;  // <= 1024
    hist_kernel<<<(E + 255) / 256, 256, 0, stream>>>(dst, counts, E);
    blk_reduce_kernel<<<nb, 256, 0, stream>>>(counts, bsum, N);
    blk_scan_kernel<<<1, 1024, 0, stream>>>(bsum, nb);
    rowptr_fill_kernel<<<nb, 256, 0, stream>>>(counts, bsum, rowptr, N);
    fill_kernel<<<(E + 255) / 256, 256, 0, stream>>>(src, dst, attr, rowptr, cnt2,
                                                     src_perm, attr_perm, eidp, E);

    cvt_bf16_kernel<<<(N * 64 + 255) / 256, 256, 0, stream>>>(x, xb, N * 64);
    W12 ws;
    for (int l = 0; l < 3; ++l) {
        ws.p[l * 4 + 0] = Wq[l]; ws.p[l * 4 + 1] = Wk[l];
        ws.p[l * 4 + 2] = Wv[l]; ws.p[l * 4 + 3] = Ws[l];
    }
    prepack_all_kernel<<<dim3(32, 12), 256, 0, stream>>>(ws, wt);

    for (int l = 0; l < 3; ++l) {
        float* SKIP = (l < 2) ? hA : z_out;
        const unsigned short* Xin = (const unsigned short*)((l == 0) ? xb : hb);
        gemm_mfma_kernel<<<dim3((N + 63) / 64, 4), 256, 0, stream>>>(
            Xin, (const unsigned short*)(wt + (size_t)l * 4 * 8192),
            bq[l], bk[l], bv[l], bs[l],
            qb, (unsigned short*)kb, (unsigned short*)vb, SKIP, N);
        node_fused_kernel<<<(N + 3) / 4, 256, 0, stream>>>(
            qb, kb, vb, We[l], be[l], rowptr, src_perm, attr_perm, eidp,
            alpha_perm, alpha_out[l], SKIP, z_out, hb,
            (l < 2) ? ln_g[l] : ln_g[0], (l < 2) ? ln_b[l] : ln_b[0],
            (l < 2) ? 1 : 0, N);
    }

    pool_kernel<<<(N + 31) / 32, 128, 0, stream>>>(z_out, batch, pool, gcnt, N);
    classifier_kernel<<<1, 128, 0, stream>>>(pool, gcnt, batch, fc1_w, fc1_b,
                                             cln_g, cln_b, fc2_w, fc2_b,
                                             zsel_out, probs_out);
}